// Round 9
// baseline (447.882 us; speedup 1.0000x reference)
//
#include <hip/hip_runtime.h>
#include <math.h>

// ---------------------------------------------------------------------------
// Problem constants (B=8, N1=128, N2=256, D=128, L=3, NH=54)
// Packed row space: rows 0..1023 = ligand (b*128+i), rows 1024..3071 = target
// (1024 + b*256 + j).
// ---------------------------------------------------------------------------
#define BB 8
#define N1C 128
#define N2C 256
#define DC 128
#define NHC 54
#define ROWS_L 1024
#define ROWS_T 2048
#define ROWS_ALL 3072

// ---------------------------------------------------------------------------
// Reductions (wave64)
// ---------------------------------------------------------------------------
__device__ __forceinline__ float wredSum(float v) {
#pragma unroll
  for (int o = 32; o > 0; o >>= 1) v += __shfl_down(v, o);
  return v;
}
__device__ float blockSum(float v) {
  __shared__ float red[9];
  v = wredSum(v);
  int lane = threadIdx.x & 63, wid = threadIdx.x >> 6;
  __syncthreads();
  if (lane == 0) red[wid] = v;
  __syncthreads();
  if (threadIdx.x == 0) {
    float s = 0.f;
    int nw = (blockDim.x + 63) >> 6;
    for (int i = 0; i < nw; ++i) s += red[i];
    red[8] = s;
  }
  __syncthreads();
  return red[8];
}

// ---------------------------------------------------------------------------
// k_prep: merged adj12 + embedding + GAT-weight-fuse + GRU-weight-transpose.
// grid = 1024 + 384 + 99 + 1152 = 2659 blocks, 256 threads.
// ---------------------------------------------------------------------------
__global__ __launch_bounds__(256) void k_prep(
    const float* __restrict__ LP, const float* __restrict__ TP,
    float* __restrict__ AD, const float* __restrict__ LH,
    const float* __restrict__ TH, const float* __restrict__ EW,
    float* __restrict__ H0, const float* __restrict__ GWp,
    const float* __restrict__ GBp, const float* __restrict__ ATT,
    float* __restrict__ WA, float* __restrict__ bA,
    const float* __restrict__ IH, const float* __restrict__ HH,
    float* __restrict__ GIHT, float* __restrict__ GHHT) {
  int bid = blockIdx.x, tid = threadIdx.x;
  if (bid < 1024) {  // ---- adj12 ----
    long idx = (long)bid * 256 + tid;
    int j = idx & (N2C - 1);
    long t = idx >> 8;
    int i = (int)(t & (N1C - 1));
    int b = (int)(t >> 7);
    float dx = LP[((long)b * N1C + i) * 3 + 0] - TP[((long)b * N2C + j) * 3 + 0];
    float dy = LP[((long)b * N1C + i) * 3 + 1] - TP[((long)b * N2C + j) * 3 + 1];
    float dz = LP[((long)b * N1C + i) * 3 + 2] - TP[((long)b * N2C + j) * 3 + 2];
    float d = sqrtf(dx * dx + dy * dy + dz * dz + 1e-10f);
    if (d < 0.5f) d = 1e10f;
    AD[idx] = (d <= 5.0f && d > 1e-3f) ? 1.f : 0.f;
  } else if (bid < 1024 + 384) {  // ---- embedding, 8 rows/block ----
    int r0 = (bid - 1024) * 8;
    __shared__ float xs[8][NHC];
    for (int t = tid; t < 8 * NHC; t += 256) {
      int rr = r0 + t / NHC, c = t % NHC;
      xs[t / NHC][c] = (rr < ROWS_L) ? LH[(long)rr * NHC + c]
                                     : TH[(long)(rr - ROWS_L) * NHC + c];
    }
    __syncthreads();
    int d = tid & 127, rb = (tid >> 7) * 4;
    float a[4] = {0.f, 0.f, 0.f, 0.f};
#pragma unroll 6
    for (int k = 0; k < NHC; ++k) {
      float wv = EW[(long)k * DC + d];
#pragma unroll
      for (int r = 0; r < 4; ++r) a[r] += xs[rb + r][k] * wv;
    }
#pragma unroll
    for (int r = 0; r < 4; ++r) H0[(long)(r0 + rb + r) * DC + d] = a[r];
  } else if (bid < 1024 + 384 + 99) {  // ---- wfuse: WA_l = W_l @ ATT_l ----
    int q = bid - 1408;
    int l = q / 33, bx = q % 33;
    const float* Wl = GWp + (long)l * DC * DC;
    const float* Al = ATT + (long)l * DC * DC;
    if (bx == 32) {
      if (tid < 128) {
        float acc = 0.f;
#pragma unroll 8
        for (int m = 0; m < DC; ++m)
          acc += GBp[l * DC + m] * Al[(long)m * DC + tid];
        bA[l * DC + tid] = acc;
      }
    } else {
      __shared__ float xs2[4][DC];
      int r0 = bx * 4;
      for (int t = tid; t < 4 * DC; t += 256)
        xs2[t >> 7][t & 127] = Wl[(long)r0 * DC + t];
      __syncthreads();
      if (tid < 128) {
        int d = tid;
        float a0 = 0.f, a1 = 0.f, a2 = 0.f, a3 = 0.f;
#pragma unroll 8
        for (int m = 0; m < DC; ++m) {
          float av = Al[(long)m * DC + d];
          a0 += xs2[0][m] * av;
          a1 += xs2[1][m] * av;
          a2 += xs2[2][m] * av;
          a3 += xs2[3][m] * av;
        }
        float* out = WA + (long)l * DC * DC + (long)r0 * DC + d;
        out[0] = a0;
        out[DC] = a1;
        out[2 * DC] = a2;
        out[3 * DC] = a3;
      }
    }
  } else {  // ---- GRU weight transposes ----
    long idx = (long)(bid - 1507) * 256 + tid;
    if (idx < 6L * 49152) {
      int a = (int)(idx / 49152);
      int rem = (int)(idx % 49152);
      int l = a >> 1, whh = a & 1;
      int c = rem / 384, rr = rem % 384;
      const float* src = (whh ? HH : IH) + (long)l * 49152;
      float* dst = (whh ? GHHT : GIHT) + (long)l * 49152;
      dst[(long)c * 384 + rr] = src[(long)rr * 128 + c];
    }
  }
}

// ---------------------------------------------------------------------------
// Dual-head linear: Y1 = X@W1(+b1), Y2 = X@W2(+b2).  4 rows/block, 256 thr
// (tid>>7 = head, d = tid&127).  X staged TRANSPOSED -> one b128 broadcast
// per k.  trans=1 stores Yh[b][d][row].
// ---------------------------------------------------------------------------
__global__ __launch_bounds__(256) void k_lin2h(
    const float* __restrict__ X, const float* __restrict__ W1,
    const float* __restrict__ b1, const float* __restrict__ W2,
    const float* __restrict__ b2, float* __restrict__ Y1, float* __restrict__ Y2,
    int rpb, int trans) {
  int r0 = blockIdx.x * 4;
  __shared__ float xs_t[DC][4];
  int tid = threadIdx.x;
  for (int t = tid; t < 4 * DC; t += 256) {
    int r = t >> 7, c = t & 127;
    xs_t[c][r] = X[(long)(r0 + r) * DC + c];
  }
  __syncthreads();
  int h = tid >> 7, d = tid & 127;
  const float* W = h ? W2 : W1;
  const float* bp = h ? b2 : b1;
  float* Y = h ? Y2 : Y1;
  float a0 = 0.f, a1 = 0.f, a2 = 0.f, a3 = 0.f;
#pragma unroll 8
  for (int k = 0; k < DC; ++k) {
    float4 xv = *(const float4*)&xs_t[k][0];
    float wv = W[(long)k * DC + d];
    a0 = fmaf(xv.x, wv, a0);
    a1 = fmaf(xv.y, wv, a1);
    a2 = fmaf(xv.z, wv, a2);
    a3 = fmaf(xv.w, wv, a3);
  }
  float bv = bp ? bp[d] : 0.f;
  float v[4] = {a0 + bv, a1 + bv, a2 + bv, a3 + bv};
  if (!trans) {
#pragma unroll
    for (int r = 0; r < 4; ++r) Y[(long)(r0 + r) * DC + d] = v[r];
  } else {
    int b = r0 / rpb, rin = r0 - b * rpb;  // 4 | rpb, so same batch
#pragma unroll
    for (int r = 0; r < 4; ++r)
      Y[((long)b * DC + d) * rpb + rin + r] = v[r];
  }
}

// ---------------------------------------------------------------------------
// k_ea2: ea[b,j,k] = e1_j.nt_k + nt_j.e1_k, masked by adjacency at write.
// Register-tiled: 32x64 tile, 256 thr, 2x4 outputs/thread.  Merged
// ligand+target: 64 + 256 = 320 blocks.
// ---------------------------------------------------------------------------
__global__ __launch_bounds__(256) void k_ea2(const float* __restrict__ NTp,
                                             const float* __restrict__ E1p,
                                             const float* __restrict__ ADJL,
                                             const float* __restrict__ ADJT,
                                             float* __restrict__ EAL,
                                             float* __restrict__ EAT) {
  int id = blockIdx.x;
  int N, base, j0, k0, b;
  const float* ADJ;
  float* EA;
  if (id < 64) {
    b = id >> 3;
    int rem = id & 7;
    N = N1C;
    base = b * N1C;
    j0 = (rem >> 1) * 32;
    k0 = (rem & 1) * 64;
    ADJ = ADJL + (long)b * N1C * N1C;
    EA = EAL + (long)b * N1C * N1C;
  } else {
    int q = id - 64;
    b = q >> 5;
    int rem = q & 31;
    N = N2C;
    base = ROWS_L + b * N2C;
    j0 = (rem >> 2) * 32;
    k0 = (rem & 3) * 64;
    ADJ = ADJT + (long)b * N2C * N2C;
    EA = EAT + (long)b * N2C * N2C;
  }
  __shared__ float aj_e1[32][34], aj_nt[32][34];
  __shared__ float bk_e1[32][68], bk_nt[32][68];
  int tid = threadIdx.x, tx = tid & 15, ty = tid >> 4;
  float acc[2][4];
#pragma unroll
  for (int r = 0; r < 2; ++r)
#pragma unroll
    for (int c = 0; c < 4; ++c) acc[r][c] = 0.f;
  for (int kc = 0; kc < DC; kc += 32) {
    __syncthreads();
    for (int t = tid; t < 1024; t += 256) {
      int kk = t & 31, rr = t >> 5;
      aj_e1[kk][rr] = E1p[(long)(base + j0 + rr) * DC + kc + kk];
      aj_nt[kk][rr] = NTp[(long)(base + j0 + rr) * DC + kc + kk];
    }
    for (int t = tid; t < 2048; t += 256) {
      int kk = t & 31, cc = t >> 5;
      bk_e1[kk][cc] = E1p[(long)(base + k0 + cc) * DC + kc + kk];
      bk_nt[kk][cc] = NTp[(long)(base + k0 + cc) * DC + kc + kk];
    }
    __syncthreads();
#pragma unroll
    for (int kk = 0; kk < 32; ++kk) {
      float2 ae = *(const float2*)&aj_e1[kk][ty * 2];
      float2 an = *(const float2*)&aj_nt[kk][ty * 2];
      float4 bn = *(const float4*)&bk_nt[kk][tx * 4];
      float4 be = *(const float4*)&bk_e1[kk][tx * 4];
      acc[0][0] = fmaf(ae.x, bn.x, fmaf(an.x, be.x, acc[0][0]));
      acc[0][1] = fmaf(ae.x, bn.y, fmaf(an.x, be.y, acc[0][1]));
      acc[0][2] = fmaf(ae.x, bn.z, fmaf(an.x, be.z, acc[0][2]));
      acc[0][3] = fmaf(ae.x, bn.w, fmaf(an.x, be.w, acc[0][3]));
      acc[1][0] = fmaf(ae.y, bn.x, fmaf(an.y, be.x, acc[1][0]));
      acc[1][1] = fmaf(ae.y, bn.y, fmaf(an.y, be.y, acc[1][1]));
      acc[1][2] = fmaf(ae.y, bn.z, fmaf(an.y, be.z, acc[1][2]));
      acc[1][3] = fmaf(ae.y, bn.w, fmaf(an.y, be.w, acc[1][3]));
    }
  }
#pragma unroll
  for (int r = 0; r < 2; ++r) {
    long rowi = (long)(j0 + ty * 2 + r) * N + k0 + tx * 4;
    float4 ad = *(const float4*)&ADJ[rowi];
    float4 o;
    o.x = (ad.x > 1e-6f) ? acc[r][0] : -9e15f;
    o.y = (ad.y > 1e-6f) ? acc[r][1] : -9e15f;
    o.z = (ad.z > 1e-6f) ? acc[r][2] : -9e15f;
    o.w = (ad.w > 1e-6f) ? acc[r][3] : -9e15f;
    *(float4*)&EA[rowi] = o;
  }
}

// ---------------------------------------------------------------------------
// k_smagg3: row-softmax + aggregate + gated residual.  16 rows/block,
// 512 threads (16 rowgrp x 32 dgrp x 4 cols).  grid (16, 8, 2).
// ---------------------------------------------------------------------------
__global__ __launch_bounds__(512) void k_smagg3(
    const float* __restrict__ EAL, const float* __restrict__ EAT,
    const float* __restrict__ NTp, const float* __restrict__ Xp,
    const float* __restrict__ GW, const float* __restrict__ GB,
    float* __restrict__ Y) {
  int z = blockIdx.z;
  int N = z ? N2C : N1C;
  if (blockIdx.x * 16 >= N) return;
  int ls = z ? 8 : 7;
  int baseRow = z ? ROWS_L : 0;
  const float* EA = z ? EAT : EAL;
  int b = blockIdx.y, i0 = blockIdx.x * 16;
  __shared__ float ps[16][N2C + 4];
  __shared__ float col[32][DC + 4];
  __shared__ float red[16];
  int tid = threadIdx.x;
  const float* EAb = EA + (long)b * N * N + (long)i0 * N;
  for (int t = tid; t < 16 * N; t += 512)
    ps[t >> ls][t & (N - 1)] = EAb[t];
  __syncthreads();
  int r = tid >> 5, l = tid & 31;  // 16 rows x 32 lanes
  {                                // softmax
    float m = -INFINITY;
    for (int k = l; k < N; k += 32) m = fmaxf(m, ps[r][k]);
#pragma unroll
    for (int o = 16; o > 0; o >>= 1) m = fmaxf(m, __shfl_xor(m, o));
    float s = 0.f;
    for (int k = l; k < N; k += 32) {
      float p = expf(ps[r][k] - m);
      ps[r][k] = p;
      s += p;
    }
#pragma unroll
    for (int o = 16; o > 0; o >>= 1) s += __shfl_xor(s, o);
    float inv = 1.f / s;
    for (int k = l; k < N; k += 32) ps[r][k] *= inv;
  }
  // aggregate: row r, cols d0..d0+3
  int d0 = l * 4;
  float a0 = 0.f, a1 = 0.f, a2 = 0.f, a3 = 0.f;
  const float* NTb = NTp + (long)(baseRow + b * N) * DC;
  for (int k0 = 0; k0 < N; k0 += 32) {
    __syncthreads();
    for (int t = tid; t < 32 * DC; t += 512)
      col[t >> 7][t & 127] = NTb[(long)(k0 + (t >> 7)) * DC + (t & 127)];
    __syncthreads();
#pragma unroll 8
    for (int kk = 0; kk < 32; ++kk) {
      float4 c4 = *(const float4*)&col[kk][d0];
      float p = ps[r][k0 + kk];
      a0 = fmaf(p, c4.x, a0);
      a1 = fmaf(p, c4.y, a1);
      a2 = fmaf(p, c4.z, a2);
      a3 = fmaf(p, c4.w, a3);
    }
  }
  // gate
  float4 gwd = *(const float4*)&GW[d0];
  float4 gwo = *(const float4*)&GW[DC + d0];
  float4 x4 = *(const float4*)&Xp[(long)(baseRow + b * N + i0 + r) * DC + d0];
  float o0 = fmaxf(a0, 0.f), o1 = fmaxf(a1, 0.f);
  float o2 = fmaxf(a2, 0.f), o3 = fmaxf(a3, 0.f);
  float part = x4.x * gwd.x + o0 * gwo.x + x4.y * gwd.y + o1 * gwo.y +
               x4.z * gwd.z + o2 * gwo.z + x4.w * gwd.w + o3 * gwo.w;
#pragma unroll
  for (int o = 16; o > 0; o >>= 1) part += __shfl_xor(part, o);
  if (l == 0) red[r] = part;
  __syncthreads();
  float g = 1.f / (1.f + expf(-(red[r] + GB[0])));
  float4 y;
  y.x = g * x4.x + (1.f - g) * o0;
  y.y = g * x4.y + (1.f - g) * o1;
  y.z = g * x4.z + (1.f - g) * o2;
  y.w = g * x4.w + (1.f - g) * o3;
  *(float4*)&Y[(long)(baseRow + b * N + i0 + r) * DC + d0] = y;
}

// ---------------------------------------------------------------------------
// k_msg2v: msg = relu(t1 + max_j m2_j * ev_ij).  8 rows/block, 256 thr
// (32 dgrp x 8 rows).  grid (32, 8, 2): z=0 ligand (x<16), z=1 target.
// ---------------------------------------------------------------------------
__global__ __launch_bounds__(256) void k_msg2v(const float* __restrict__ T1,
                                               const float* __restrict__ M2,
                                               const float* __restrict__ EV,
                                               float* __restrict__ MSG) {
  int z = blockIdx.z, b = blockIdx.y;
  int Ni = z ? N2C : N1C, Nj = z ? N1C : N2C;
  if (blockIdx.x * 8 >= Ni) return;
  int t1off = z ? ROWS_L : 0, m2off = z ? 0 : ROWS_L;
  long ev_is = z ? 1L : (long)N2C, ev_js = z ? (long)N2C : 1L;
  int i0 = blockIdx.x * 8;
  __shared__ float m2s[32][DC + 4];
  __shared__ float evs[8][36];
  int dgrp = threadIdx.x & 31, row = threadIdx.x >> 5;
  int d0 = dgrp * 4;
  float a0 = -INFINITY, a1 = -INFINITY, a2 = -INFINITY, a3 = -INFINITY;
  const float* M2b = M2 + (long)(m2off + b * Nj) * DC;
  const float* EVb = EV + (long)b * (N1C * N2C);
  for (int j0 = 0; j0 < Nj; j0 += 32) {
    __syncthreads();
    for (int t = threadIdx.x; t < 32 * DC; t += 256)
      m2s[t >> 7][t & 127] = M2b[(long)(j0 + (t >> 7)) * DC + (t & 127)];
    for (int t = threadIdx.x; t < 256; t += 256)
      evs[t >> 5][t & 31] =
          EVb[(long)(i0 + (t >> 5)) * ev_is + (long)(j0 + (t & 31)) * ev_js];
    __syncthreads();
#pragma unroll 8
    for (int jj = 0; jj < 32; ++jj) {
      float4 m4 = *(const float4*)&m2s[jj][d0];
      float e = evs[row][jj];
      a0 = fmaxf(a0, m4.x * e);
      a1 = fmaxf(a1, m4.y * e);
      a2 = fmaxf(a2, m4.z * e);
      a3 = fmaxf(a3, m4.w * e);
    }
  }
  long grow = t1off + (long)b * Ni + i0 + row;
  float4 t4 = *(const float4*)&T1[grow * DC + d0];
  float4 o;
  o.x = fmaxf(t4.x + a0, 0.f);
  o.y = fmaxf(t4.y + a1, 0.f);
  o.z = fmaxf(t4.z + a2, 0.f);
  o.w = fmaxf(t4.w + a3, 0.f);
  *(float4*)&MSG[grow * DC + d0] = o;
}

// ---------------------------------------------------------------------------
// Fused GRU, 8 rows/block (384 blocks), 384 threads.  Halves L2 weight
// traffic vs 4-row version; 2 global b32 per 16 FMA.
// ---------------------------------------------------------------------------
__global__ __launch_bounds__(384) void k_gruf(
    const float* __restrict__ MSGp, const float* __restrict__ Hp,
    const float* __restrict__ WihT, const float* __restrict__ WhhT,
    const float* __restrict__ bih, const float* __restrict__ bhh,
    float* __restrict__ Y) {
  const int D = DC;
  int r0 = blockIdx.x * 8;
  __shared__ float xs_t[DC][8], hs_t[DC][8];
  __shared__ float gis[8][384], ghs[8][384];
  int tid = threadIdx.x;
  for (int t = tid; t < 8 * DC; t += 384) {
    int r = t >> 7, c = t & 127;
    xs_t[c][r] = MSGp[(long)(r0 + r) * D + c];
    hs_t[c][r] = Hp[(long)(r0 + r) * D + c];
  }
  __syncthreads();
  int dd = tid;  // 0..383
  float ai[8], ah[8];
#pragma unroll
  for (int r = 0; r < 8; ++r) { ai[r] = 0.f; ah[r] = 0.f; }
#pragma unroll 4
  for (int k = 0; k < DC; ++k) {
    float4 xv0 = *(const float4*)&xs_t[k][0];
    float4 xv1 = *(const float4*)&xs_t[k][4];
    float4 hv0 = *(const float4*)&hs_t[k][0];
    float4 hv1 = *(const float4*)&hs_t[k][4];
    float wi = WihT[(long)k * 384 + dd];
    float wh = WhhT[(long)k * 384 + dd];
    ai[0] = fmaf(xv0.x, wi, ai[0]);
    ai[1] = fmaf(xv0.y, wi, ai[1]);
    ai[2] = fmaf(xv0.z, wi, ai[2]);
    ai[3] = fmaf(xv0.w, wi, ai[3]);
    ai[4] = fmaf(xv1.x, wi, ai[4]);
    ai[5] = fmaf(xv1.y, wi, ai[5]);
    ai[6] = fmaf(xv1.z, wi, ai[6]);
    ai[7] = fmaf(xv1.w, wi, ai[7]);
    ah[0] = fmaf(hv0.x, wh, ah[0]);
    ah[1] = fmaf(hv0.y, wh, ah[1]);
    ah[2] = fmaf(hv0.z, wh, ah[2]);
    ah[3] = fmaf(hv0.w, wh, ah[3]);
    ah[4] = fmaf(hv1.x, wh, ah[4]);
    ah[5] = fmaf(hv1.y, wh, ah[5]);
    ah[6] = fmaf(hv1.z, wh, ah[6]);
    ah[7] = fmaf(hv1.w, wh, ah[7]);
  }
  float bi = bih[dd], bh = bhh[dd];
#pragma unroll
  for (int r = 0; r < 8; ++r) {
    gis[r][dd] = ai[r] + bi;
    ghs[r][dd] = ah[r] + bh;
  }
  __syncthreads();
  for (int t = tid; t < 8 * DC; t += 384) {
    int r = t >> 7, d = t & 127;
    float ir = gis[r][d], iz = gis[r][d + 128], inn = gis[r][d + 256];
    float hr = ghs[r][d], hz = ghs[r][d + 128], hn = ghs[r][d + 256];
    float rg = 1.f / (1.f + expf(-(ir + hr)));
    float zg = 1.f / (1.f + expf(-(iz + hz)));
    float ng = tanhf(inn + rg * hn);
    Y[(long)(r0 + r) * D + d] = (1.f - zg) * ng + zg * hs_t[d][r];
  }
}

// ---------------------------------------------------------------------------
// Pairwise physics + analytic grad/Hessian partials.  2 ligand atoms per
// block (halves VAT/VBT L2 traffic).  grid (64, 8), 256 threads (j).
// ---------------------------------------------------------------------------
__global__ __launch_bounds__(256) void k_pair(
    const float* __restrict__ UA, const float* __restrict__ VAT,
    const float* __restrict__ UB, const float* __restrict__ VBT,
    const float* __restrict__ AW2, const float* __restrict__ AB2,
    const float* __restrict__ BW2, const float* __restrict__ BB2,
    const float* __restrict__ LP, const float* __restrict__ TP,
    const float* __restrict__ LVDW, const float* __restrict__ TVDW,
    const float* __restrict__ LNM, const float* __restrict__ TNM,
    const float* __restrict__ II, const float* __restrict__ HBC,
    const float* __restrict__ HPC, float* __restrict__ PART) {
  const int D = DC, N1 = N1C, N2 = N2C;
  int i0 = blockIdx.x * 2, b = blockIdx.y, j = threadIdx.x;
  __shared__ float ua[2][128], ub[2][128], wa2[128], wb2[128];
  if (j < 128) {
    long rb = ((long)b * N1 + i0) * D + j;
    ua[0][j] = UA[rb];
    ub[0][j] = UB[rb];
    wa2[j] = AW2[j];
    wb2[j] = BW2[j];
  } else {
    int jj = j - 128;
    long rb = ((long)b * N1 + i0 + 1) * D + jj;
    ua[1][jj] = UA[rb];
    ub[1][jj] = UB[rb];
  }
  __syncthreads();
  const float* vat = VAT + (long)b * D * N2;
  const float* vbt = VBT + (long)b * D * N2;
  float dotA[2] = {0.f, 0.f}, dotB[2] = {0.f, 0.f};
#pragma unroll 4
  for (int d = 0; d < D; ++d) {
    float va = vat[(long)d * N2 + j];
    float vb = vbt[(long)d * N2 + j];
    dotA[0] += fmaxf(ua[0][d] + va, 0.f) * wa2[d];
    dotA[1] += fmaxf(ua[1][d] + va, 0.f) * wa2[d];
    dotB[0] += fmaxf(ub[0][d] + vb, 0.f) * wb2[d];
    dotB[1] += fmaxf(ub[1][d] + vb, 0.f) * wb2[d];
  }
  float hb2 = HBC[0] * HBC[0], hp2 = HPC[0] * HPC[0];
  float tx = TP[((long)b * N2 + j) * 3 + 0];
  float ty = TP[((long)b * N2 + j) * 3 + 1];
  float tz = TP[((long)b * N2 + j) * 3 + 2];
  float tvd = TVDW[b * N2 + j];
  float tnm = TNM[b * N2 + j];
  float res[2][8];
#pragma unroll
  for (int ii = 0; ii < 2; ++ii) {
    int i = i0 + ii;
    float A_raw = 1.f / (1.f + expf(-(dotA[ii] + AB2[0])));
    float A_vdw = A_raw * (0.0356f - 0.0178f) + 0.0178f;
    float B_raw = tanhf(dotB[ii] + BB2[0]) * 0.2f;

    float lx = LP[((long)b * N1 + i) * 3 + 0];
    float ly = LP[((long)b * N1 + i) * 3 + 1];
    float lz = LP[((long)b * N1 + i) * 3 + 2];
    float dx = lx - tx, dy = ly - ty, dz = lz - tz;
    float s2 = dx * dx + dy * dy + dz * dz + 1e-10f;
    float draw = sqrtf(s2);
    bool clamped = draw < 0.5f;
    float dmv = clamped ? 1e10f : draw;

    float dm0 = LVDW[b * N1 + i] + tvd + B_raw;
    float dm0c = (dm0 < 1e-4f) ? 1.f : dm0;
    float valid = LNM[b * N1 + i] * tnm;

    float rr = dm0c / dmv;
    float r2 = rr * rr, r6 = r2 * r2 * r2;
    float fv = r6 * r6 - 2.f * r6;
    float evdw = A_vdw * (fminf(fv, 100.f) * valid);

    float dmd = dmv - dm0;
    long ii0x = ((long)b * 3) * N1 * N2 + (long)i * N2 + j;
    float I0 = II[ii0x];
    float I1 = II[ii0x + (long)N1 * N2];
    float I2 = II[ii0x + 2L * N1 * N2];
    float u0 = dmd * I0 / (-0.7f);
    float u1 = dmd * I1 / (-0.7f);
    float vv = (1.5f - dmd) * I2;
    float ehb = fminf(fmaxf(u0, 0.f), 1.f) * (-hb2);
    float emt = fminf(fmaxf(u1, 0.f), 1.f) * (-hb2);
    float ehp = fminf(fmaxf(vv, 0.f), 1.f) * (-hp2);

    float gx = 0.f, gy = 0.f, gz = 0.f, d2t = 0.f;
    if (!clamped) {
      float Ep = 0.f, Epp = 0.f;
      if (fv < 100.f) {
        float c = A_vdw * valid;
        Ep += c * (-12.f) * r6 * (r6 - 1.f) / draw;
        Epp += c * r6 * (156.f * r6 - 84.f) / s2;
      }
      if (u0 > 0.f && u0 < 1.f) Ep += hb2 * I0 * (1.f / 0.7f);
      if (u1 > 0.f && u1 < 1.f) Ep += hb2 * I1 * (1.f / 0.7f);
      if (vv > 0.f && vv < 1.f) Ep += hp2 * I2;
      float invd = 1.f / draw;
      gx = Ep * dx * invd;
      gy = Ep * dy * invd;
      gz = Ep * dz * invd;
      float T = dx + dy + dz;
      float tt = T * T / s2;
      d2t = Epp * tt + Ep * (3.f - tt) * invd;
    }
    res[ii][0] = evdw;
    res[ii][1] = ehb;
    res[ii][2] = emt;
    res[ii][3] = ehp;
    res[ii][4] = gx;
    res[ii][5] = gy;
    res[ii][6] = gz;
    res[ii][7] = d2t;
  }
#pragma unroll
  for (int ii = 0; ii < 2; ++ii) {
    float o[8];
#pragma unroll
    for (int q = 0; q < 8; ++q) o[q] = blockSum(res[ii][q]);
    if (j == 0) {
      float* p = PART + ((long)b * N1 + i0 + ii) * 8;
#pragma unroll
      for (int q = 0; q < 8; ++q) p[q] = o[q];
    }
  }
}

// final deterministic reduction + output assembly (34 floats)
__global__ void k_final(const float* __restrict__ PART, const float* __restrict__ ROT,
                        const float* __restrict__ RC, float* __restrict__ OUT) {
  const int N1 = N1C;
  __shared__ float s[8][8];
  int t = threadIdx.x;
  if (t < 64) {
    int b = t >> 3, k1 = t & 7;
    float acc = 0.f;
    for (int i = 0; i < N1; ++i) acc += PART[((long)b * N1 + i) * 8 + k1];
    s[b][k1] = acc;
  }
  __syncthreads();
  if (t == 0) {
    float rcc = RC[0] * RC[0];
    float der1 = 0.f, der2 = 0.f;
    for (int b = 0; b < 8; ++b) {
      float w = 1.f / (1.f + rcc * ROT[b]);
      OUT[b * 4 + 0] = s[b][0] * w;
      OUT[b * 4 + 1] = s[b][1] * w;
      OUT[b * 4 + 2] = s[b][2] * w;
      OUT[b * 4 + 3] = s[b][3] * w;
      for (int c = 0; c < 3; ++c) {
        float S = s[b][4 + c] * w;
        der1 += S * S;
      }
      der2 += s[b][7] * w;
    }
    OUT[32] = der1 / 24.f;
    OUT[33] = -der2 / 8.f;
  }
}

// ---------------------------------------------------------------------------
// Host-side orchestration
// ---------------------------------------------------------------------------
extern "C" void kernel_launch(void* const* d_in, const int* in_sizes, int n_in,
                              void* d_out, int out_size, void* d_ws, size_t ws_size,
                              hipStream_t stream) {
  (void)in_sizes; (void)n_in; (void)out_size; (void)ws_size;
  const int D = DC;

  const float* ligand_h   = (const float*)d_in[0];
  const float* ligand_adj = (const float*)d_in[1];
  const float* target_h   = (const float*)d_in[2];
  const float* target_adj = (const float*)d_in[3];
  const float* inter_ind  = (const float*)d_in[4];
  const float* ligand_pos = (const float*)d_in[5];
  const float* target_pos = (const float*)d_in[6];
  const float* rotor      = (const float*)d_in[7];
  const float* lvdw       = (const float*)d_in[8];
  const float* tvdw       = (const float*)d_in[9];
  const float* lnm        = (const float*)d_in[12];
  const float* tnm        = (const float*)d_in[13];
  const float* emb_w      = (const float*)d_in[14];
  const float* gat_w      = (const float*)d_in[15];
  const float* gat_b      = (const float*)d_in[16];
  const float* gat_att    = (const float*)d_in[17];
  const float* gat_gate_w = (const float*)d_in[18];
  const float* gat_gate_b = (const float*)d_in[19];
  const float* int_wt_w   = (const float*)d_in[20];
  const float* int_wt_b   = (const float*)d_in[21];
  const float* int_mt_w   = (const float*)d_in[22];
  const float* int_mt_b   = (const float*)d_in[23];
  const float* gru_w_ih   = (const float*)d_in[24];
  const float* gru_w_hh   = (const float*)d_in[25];
  const float* gru_b_ih   = (const float*)d_in[26];
  const float* gru_b_hh   = (const float*)d_in[27];
  const float* A_w1       = (const float*)d_in[28];
  const float* A_b1       = (const float*)d_in[29];
  const float* A_w2       = (const float*)d_in[30];
  const float* A_b2       = (const float*)d_in[31];
  const float* B_w1       = (const float*)d_in[32];
  const float* B_b1       = (const float*)d_in[33];
  const float* B_w2       = (const float*)d_in[34];
  const float* B_b2       = (const float*)d_in[35];
  const float* hb_c       = (const float*)d_in[36];
  const float* hp_c       = (const float*)d_in[37];
  const float* rc_c       = (const float*)d_in[38];

  // workspace carve (floats)
  float* w = (float*)d_ws;
  auto take = [&](size_t n) { float* p = w; w += n; return p; };
  float* H0    = take((size_t)ROWS_ALL * DC);   // 393216
  float* H1    = take((size_t)ROWS_ALL * DC);
  float* NT    = take((size_t)ROWS_ALL * DC);
  float* E1    = take((size_t)ROWS_ALL * DC);
  float* EAL   = take((size_t)BB * N1C * N1C);  // 131072
  float* EAT   = take((size_t)BB * N2C * N2C);  // 524288
  float* ADJ12 = take((size_t)BB * N1C * N2C);  // 262144
  float* WA    = take((size_t)3 * DC * DC);     // 49152
  float* bA    = take((size_t)3 * DC);
  float* GIHT  = take((size_t)3 * DC * 384);    // 147456
  float* GHHT  = take((size_t)3 * DC * 384);
  float* PART  = take((size_t)BB * N1C * 8);
  // phase-disjoint aliases
  float* T1  = NT;
  float* M2  = E1;
  float* MSG = EAT;           // 393216 <= 524288
  float* UA  = EAL;           // 131072
  float* UB  = EAT;           // 131072 (front of EAT)
  float* VAT = NT;            // 262144 <= 393216
  float* VBT = E1;            // 262144

  // merged prep: adj12 + embedding + WA fuse + GRU weight transposes
  k_prep<<<2659, 256, 0, stream>>>(ligand_pos, target_pos, ADJ12, ligand_h,
                                   target_h, emb_w, H0, gat_w, gat_b, gat_att,
                                   WA, bA, gru_w_ih, gru_w_hh, GIHT, GHHT);

  float *cur = H0, *alt = H1;

  // GAT stack (3 layers)
  for (int l = 0; l < 3; ++l) {
    k_lin2h<<<ROWS_ALL / 4, 256, 0, stream>>>(
        cur, gat_w + (size_t)l * D * D, gat_b + l * D, WA + (size_t)l * D * D,
        bA + l * D, NT, E1, 1, 0);
    k_ea2<<<320, 256, 0, stream>>>(NT, E1, ligand_adj, target_adj, EAL, EAT);
    k_smagg3<<<dim3(N2C / 16, BB, 2), 512, 0, stream>>>(
        EAL, EAT, NT, cur, gat_gate_w + l * 2 * D, gat_gate_b + l, alt);
    float* t = cur; cur = alt; alt = t;
  }

  // interaction layers (both directions use OLD h)
  for (int l = 0; l < 3; ++l) {
    k_lin2h<<<ROWS_ALL / 4, 256, 0, stream>>>(
        cur, int_wt_w + (size_t)l * D * D, int_wt_b + l * D,
        int_mt_w + (size_t)l * D * D, int_mt_b + l * D, T1, M2, 1, 0);
    k_msg2v<<<dim3(32, 8, 2), 256, 0, stream>>>(T1, M2, ADJ12, MSG);
    k_gruf<<<ROWS_ALL / 8, 384, 0, stream>>>(MSG, cur, GIHT + (size_t)l * D * 384,
                                             GHHT + (size_t)l * D * 384,
                                             gru_b_ih + l * 384,
                                             gru_b_hh + l * 384, alt);
    float* t = cur; cur = alt; alt = t;
  }

  // pairwise feature precompute (U normal layout, V transposed [b][d][j])
  k_lin2h<<<ROWS_L / 4, 256, 0, stream>>>(cur, A_w1, A_b1, B_w1, B_b1, UA, UB,
                                          1, 0);
  k_lin2h<<<ROWS_T / 4, 256, 0, stream>>>(cur + (size_t)ROWS_L * DC,
                                          A_w1 + D * D, nullptr, B_w1 + D * D,
                                          nullptr, VAT, VBT, N2C, 1);

  // pairwise physics + analytic derivatives (2 atoms/block)
  k_pair<<<dim3(N1C / 2, BB), 256, 0, stream>>>(UA, VAT, UB, VBT, A_w2, A_b2,
                                                B_w2, B_b2, ligand_pos,
                                                target_pos, lvdw, tvdw, lnm,
                                                tnm, inter_ind, hb_c, hp_c,
                                                PART);

  // final reduction -> 34 outputs
  k_final<<<1, 256, 0, stream>>>(PART, rotor, rc_c, (float*)d_out);
}

// Round 10
// 371.384 us; speedup vs baseline: 1.2060x; 1.2060x over previous
//
#include <hip/hip_runtime.h>
#include <math.h>

// ---------------------------------------------------------------------------
// Problem constants (B=8, N1=128, N2=256, D=128, L=3, NH=54)
// Packed row space: rows 0..1023 = ligand (b*128+i), rows 1024..3071 = target
// (1024 + b*256 + j).
// ---------------------------------------------------------------------------
#define BB 8
#define N1C 128
#define N2C 256
#define DC 128
#define NHC 54
#define ROWS_L 1024
#define ROWS_T 2048
#define ROWS_ALL 3072

// ---------------------------------------------------------------------------
// Reductions (wave64)
// ---------------------------------------------------------------------------
__device__ __forceinline__ float wredSum(float v) {
#pragma unroll
  for (int o = 32; o > 0; o >>= 1) v += __shfl_down(v, o);
  return v;
}
__device__ float blockSum(float v) {
  __shared__ float red[9];
  v = wredSum(v);
  int lane = threadIdx.x & 63, wid = threadIdx.x >> 6;
  __syncthreads();
  if (lane == 0) red[wid] = v;
  __syncthreads();
  if (threadIdx.x == 0) {
    float s = 0.f;
    int nw = (blockDim.x + 63) >> 6;
    for (int i = 0; i < nw; ++i) s += red[i];
    red[8] = s;
  }
  __syncthreads();
  return red[8];
}

// ---------------------------------------------------------------------------
// k_prep: merged adj12 + embedding + GAT-weight-fuse + GRU-weight-transpose.
// grid = 1024 + 384 + 99 + 1152 = 2659 blocks, 256 threads.
// ---------------------------------------------------------------------------
__global__ __launch_bounds__(256) void k_prep(
    const float* __restrict__ LP, const float* __restrict__ TP,
    float* __restrict__ AD, const float* __restrict__ LH,
    const float* __restrict__ TH, const float* __restrict__ EW,
    float* __restrict__ H0, const float* __restrict__ GWp,
    const float* __restrict__ GBp, const float* __restrict__ ATT,
    float* __restrict__ WA, float* __restrict__ bA,
    const float* __restrict__ IH, const float* __restrict__ HH,
    float* __restrict__ GIHT, float* __restrict__ GHHT) {
  int bid = blockIdx.x, tid = threadIdx.x;
  if (bid < 1024) {  // ---- adj12 ----
    long idx = (long)bid * 256 + tid;
    int j = idx & (N2C - 1);
    long t = idx >> 8;
    int i = (int)(t & (N1C - 1));
    int b = (int)(t >> 7);
    float dx = LP[((long)b * N1C + i) * 3 + 0] - TP[((long)b * N2C + j) * 3 + 0];
    float dy = LP[((long)b * N1C + i) * 3 + 1] - TP[((long)b * N2C + j) * 3 + 1];
    float dz = LP[((long)b * N1C + i) * 3 + 2] - TP[((long)b * N2C + j) * 3 + 2];
    float d = sqrtf(dx * dx + dy * dy + dz * dz + 1e-10f);
    if (d < 0.5f) d = 1e10f;
    AD[idx] = (d <= 5.0f && d > 1e-3f) ? 1.f : 0.f;
  } else if (bid < 1024 + 384) {  // ---- embedding, 8 rows/block ----
    int r0 = (bid - 1024) * 8;
    __shared__ float xs[8][NHC];
    for (int t = tid; t < 8 * NHC; t += 256) {
      int rr = r0 + t / NHC, c = t % NHC;
      xs[t / NHC][c] = (rr < ROWS_L) ? LH[(long)rr * NHC + c]
                                     : TH[(long)(rr - ROWS_L) * NHC + c];
    }
    __syncthreads();
    int d = tid & 127, rb = (tid >> 7) * 4;
    float a[4] = {0.f, 0.f, 0.f, 0.f};
#pragma unroll 6
    for (int k = 0; k < NHC; ++k) {
      float wv = EW[(long)k * DC + d];
#pragma unroll
      for (int r = 0; r < 4; ++r) a[r] += xs[rb + r][k] * wv;
    }
#pragma unroll
    for (int r = 0; r < 4; ++r) H0[(long)(r0 + rb + r) * DC + d] = a[r];
  } else if (bid < 1024 + 384 + 99) {  // ---- wfuse: WA_l = W_l @ ATT_l ----
    int q = bid - 1408;
    int l = q / 33, bx = q % 33;
    const float* Wl = GWp + (long)l * DC * DC;
    const float* Al = ATT + (long)l * DC * DC;
    if (bx == 32) {
      if (tid < 128) {
        float acc = 0.f;
#pragma unroll 8
        for (int m = 0; m < DC; ++m)
          acc += GBp[l * DC + m] * Al[(long)m * DC + tid];
        bA[l * DC + tid] = acc;
      }
    } else {
      __shared__ float xs2[4][DC];
      int r0 = bx * 4;
      for (int t = tid; t < 4 * DC; t += 256)
        xs2[t >> 7][t & 127] = Wl[(long)r0 * DC + t];
      __syncthreads();
      if (tid < 128) {
        int d = tid;
        float a0 = 0.f, a1 = 0.f, a2 = 0.f, a3 = 0.f;
#pragma unroll 8
        for (int m = 0; m < DC; ++m) {
          float av = Al[(long)m * DC + d];
          a0 += xs2[0][m] * av;
          a1 += xs2[1][m] * av;
          a2 += xs2[2][m] * av;
          a3 += xs2[3][m] * av;
        }
        float* out = WA + (long)l * DC * DC + (long)r0 * DC + d;
        out[0] = a0;
        out[DC] = a1;
        out[2 * DC] = a2;
        out[3 * DC] = a3;
      }
    }
  } else {  // ---- GRU weight transposes ----
    long idx = (long)(bid - 1507) * 256 + tid;
    if (idx < 6L * 49152) {
      int a = (int)(idx / 49152);
      int rem = (int)(idx % 49152);
      int l = a >> 1, whh = a & 1;
      int c = rem / 384, rr = rem % 384;
      const float* src = (whh ? HH : IH) + (long)l * 49152;
      float* dst = (whh ? GHHT : GIHT) + (long)l * 49152;
      dst[(long)c * 384 + rr] = src[(long)rr * 128 + c];
    }
  }
}

// ---------------------------------------------------------------------------
// Dual-head linear: Y1 = X@W1(+b1), Y2 = X@W2(+b2).  8 rows/block, 256 thr
// (tid>>7 = head, d = tid&127).  X staged TRANSPOSED -> 2 b128 broadcasts
// per k feeding 8 FMA.  trans=1 stores Yh[b][d][row].
// ---------------------------------------------------------------------------
__global__ __launch_bounds__(256) void k_lin2h(
    const float* __restrict__ X, const float* __restrict__ W1,
    const float* __restrict__ b1, const float* __restrict__ W2,
    const float* __restrict__ b2, float* __restrict__ Y1, float* __restrict__ Y2,
    int rpb, int trans) {
  int r0 = blockIdx.x * 8;
  __shared__ float xs_t[DC][8];
  int tid = threadIdx.x;
  for (int t = tid; t < 8 * DC; t += 256) {
    int r = t >> 7, c = t & 127;
    xs_t[c][r] = X[(long)(r0 + r) * DC + c];
  }
  __syncthreads();
  int h = tid >> 7, d = tid & 127;
  const float* W = h ? W2 : W1;
  const float* bp = h ? b2 : b1;
  float* Y = h ? Y2 : Y1;
  float a0 = 0.f, a1 = 0.f, a2 = 0.f, a3 = 0.f;
  float a4 = 0.f, a5 = 0.f, a6 = 0.f, a7 = 0.f;
#pragma unroll 8
  for (int k = 0; k < DC; ++k) {
    float4 x0 = *(const float4*)&xs_t[k][0];
    float4 x1 = *(const float4*)&xs_t[k][4];
    float wv = W[(long)k * DC + d];
    a0 = fmaf(x0.x, wv, a0);
    a1 = fmaf(x0.y, wv, a1);
    a2 = fmaf(x0.z, wv, a2);
    a3 = fmaf(x0.w, wv, a3);
    a4 = fmaf(x1.x, wv, a4);
    a5 = fmaf(x1.y, wv, a5);
    a6 = fmaf(x1.z, wv, a6);
    a7 = fmaf(x1.w, wv, a7);
  }
  float bv = bp ? bp[d] : 0.f;
  float v[8] = {a0 + bv, a1 + bv, a2 + bv, a3 + bv,
                a4 + bv, a5 + bv, a6 + bv, a7 + bv};
  if (!trans) {
#pragma unroll
    for (int r = 0; r < 8; ++r) Y[(long)(r0 + r) * DC + d] = v[r];
  } else {
    int b = r0 / rpb, rin = r0 - b * rpb;  // 8 | rpb in our uses
#pragma unroll
    for (int r = 0; r < 8; ++r)
      Y[((long)b * DC + d) * rpb + rin + r] = v[r];
  }
}

// ---------------------------------------------------------------------------
// k_ea2: ea[b,j,k] = e1_j.nt_k + nt_j.e1_k, masked by adjacency at write.
// Register-tiled: 32x64 tile, 256 thr, 2x4 outputs/thread.  Merged
// ligand+target: 64 + 256 = 320 blocks.
// ---------------------------------------------------------------------------
__global__ __launch_bounds__(256) void k_ea2(const float* __restrict__ NTp,
                                             const float* __restrict__ E1p,
                                             const float* __restrict__ ADJL,
                                             const float* __restrict__ ADJT,
                                             float* __restrict__ EAL,
                                             float* __restrict__ EAT) {
  int id = blockIdx.x;
  int N, base, j0, k0, b;
  const float* ADJ;
  float* EA;
  if (id < 64) {
    b = id >> 3;
    int rem = id & 7;
    N = N1C;
    base = b * N1C;
    j0 = (rem >> 1) * 32;
    k0 = (rem & 1) * 64;
    ADJ = ADJL + (long)b * N1C * N1C;
    EA = EAL + (long)b * N1C * N1C;
  } else {
    int q = id - 64;
    b = q >> 5;
    int rem = q & 31;
    N = N2C;
    base = ROWS_L + b * N2C;
    j0 = (rem >> 2) * 32;
    k0 = (rem & 3) * 64;
    ADJ = ADJT + (long)b * N2C * N2C;
    EA = EAT + (long)b * N2C * N2C;
  }
  __shared__ float aj_e1[32][34], aj_nt[32][34];
  __shared__ float bk_e1[32][68], bk_nt[32][68];
  int tid = threadIdx.x, tx = tid & 15, ty = tid >> 4;
  float acc[2][4];
#pragma unroll
  for (int r = 0; r < 2; ++r)
#pragma unroll
    for (int c = 0; c < 4; ++c) acc[r][c] = 0.f;
  for (int kc = 0; kc < DC; kc += 32) {
    __syncthreads();
    for (int t = tid; t < 1024; t += 256) {
      int kk = t & 31, rr = t >> 5;
      aj_e1[kk][rr] = E1p[(long)(base + j0 + rr) * DC + kc + kk];
      aj_nt[kk][rr] = NTp[(long)(base + j0 + rr) * DC + kc + kk];
    }
    for (int t = tid; t < 2048; t += 256) {
      int kk = t & 31, cc = t >> 5;
      bk_e1[kk][cc] = E1p[(long)(base + k0 + cc) * DC + kc + kk];
      bk_nt[kk][cc] = NTp[(long)(base + k0 + cc) * DC + kc + kk];
    }
    __syncthreads();
#pragma unroll
    for (int kk = 0; kk < 32; ++kk) {
      float2 ae = *(const float2*)&aj_e1[kk][ty * 2];
      float2 an = *(const float2*)&aj_nt[kk][ty * 2];
      float4 bn = *(const float4*)&bk_nt[kk][tx * 4];
      float4 be = *(const float4*)&bk_e1[kk][tx * 4];
      acc[0][0] = fmaf(ae.x, bn.x, fmaf(an.x, be.x, acc[0][0]));
      acc[0][1] = fmaf(ae.x, bn.y, fmaf(an.x, be.y, acc[0][1]));
      acc[0][2] = fmaf(ae.x, bn.z, fmaf(an.x, be.z, acc[0][2]));
      acc[0][3] = fmaf(ae.x, bn.w, fmaf(an.x, be.w, acc[0][3]));
      acc[1][0] = fmaf(ae.y, bn.x, fmaf(an.y, be.x, acc[1][0]));
      acc[1][1] = fmaf(ae.y, bn.y, fmaf(an.y, be.y, acc[1][1]));
      acc[1][2] = fmaf(ae.y, bn.z, fmaf(an.y, be.z, acc[1][2]));
      acc[1][3] = fmaf(ae.y, bn.w, fmaf(an.y, be.w, acc[1][3]));
    }
  }
#pragma unroll
  for (int r = 0; r < 2; ++r) {
    long rowi = (long)(j0 + ty * 2 + r) * N + k0 + tx * 4;
    float4 ad = *(const float4*)&ADJ[rowi];
    float4 o;
    o.x = (ad.x > 1e-6f) ? acc[r][0] : -9e15f;
    o.y = (ad.y > 1e-6f) ? acc[r][1] : -9e15f;
    o.z = (ad.z > 1e-6f) ? acc[r][2] : -9e15f;
    o.w = (ad.w > 1e-6f) ? acc[r][3] : -9e15f;
    *(float4*)&EA[rowi] = o;
  }
}

// ---------------------------------------------------------------------------
// k_smagg3: row-softmax + aggregate + gated residual.  16 rows/block,
// 512 threads (16 rowgrp x 32 dgrp x 4 cols).  grid (16, 8, 2).
// ---------------------------------------------------------------------------
__global__ __launch_bounds__(512) void k_smagg3(
    const float* __restrict__ EAL, const float* __restrict__ EAT,
    const float* __restrict__ NTp, const float* __restrict__ Xp,
    const float* __restrict__ GW, const float* __restrict__ GB,
    float* __restrict__ Y) {
  int z = blockIdx.z;
  int N = z ? N2C : N1C;
  if (blockIdx.x * 16 >= N) return;
  int ls = z ? 8 : 7;
  int baseRow = z ? ROWS_L : 0;
  const float* EA = z ? EAT : EAL;
  int b = blockIdx.y, i0 = blockIdx.x * 16;
  __shared__ float ps[16][N2C + 4];
  __shared__ float col[32][DC + 4];
  __shared__ float red[16];
  int tid = threadIdx.x;
  const float* EAb = EA + (long)b * N * N + (long)i0 * N;
  for (int t = tid; t < 16 * N; t += 512)
    ps[t >> ls][t & (N - 1)] = EAb[t];
  __syncthreads();
  int r = tid >> 5, l = tid & 31;  // 16 rows x 32 lanes
  {                                // softmax
    float m = -INFINITY;
    for (int k = l; k < N; k += 32) m = fmaxf(m, ps[r][k]);
#pragma unroll
    for (int o = 16; o > 0; o >>= 1) m = fmaxf(m, __shfl_xor(m, o));
    float s = 0.f;
    for (int k = l; k < N; k += 32) {
      float p = expf(ps[r][k] - m);
      ps[r][k] = p;
      s += p;
    }
#pragma unroll
    for (int o = 16; o > 0; o >>= 1) s += __shfl_xor(s, o);
    float inv = 1.f / s;
    for (int k = l; k < N; k += 32) ps[r][k] *= inv;
  }
  // aggregate: row r, cols d0..d0+3
  int d0 = l * 4;
  float a0 = 0.f, a1 = 0.f, a2 = 0.f, a3 = 0.f;
  const float* NTb = NTp + (long)(baseRow + b * N) * DC;
  for (int k0 = 0; k0 < N; k0 += 32) {
    __syncthreads();
    for (int t = tid; t < 32 * DC; t += 512)
      col[t >> 7][t & 127] = NTb[(long)(k0 + (t >> 7)) * DC + (t & 127)];
    __syncthreads();
#pragma unroll 8
    for (int kk = 0; kk < 32; ++kk) {
      float4 c4 = *(const float4*)&col[kk][d0];
      float p = ps[r][k0 + kk];
      a0 = fmaf(p, c4.x, a0);
      a1 = fmaf(p, c4.y, a1);
      a2 = fmaf(p, c4.z, a2);
      a3 = fmaf(p, c4.w, a3);
    }
  }
  // gate
  float4 gwd = *(const float4*)&GW[d0];
  float4 gwo = *(const float4*)&GW[DC + d0];
  float4 x4 = *(const float4*)&Xp[(long)(baseRow + b * N + i0 + r) * DC + d0];
  float o0 = fmaxf(a0, 0.f), o1 = fmaxf(a1, 0.f);
  float o2 = fmaxf(a2, 0.f), o3 = fmaxf(a3, 0.f);
  float part = x4.x * gwd.x + o0 * gwo.x + x4.y * gwd.y + o1 * gwo.y +
               x4.z * gwd.z + o2 * gwo.z + x4.w * gwd.w + o3 * gwo.w;
#pragma unroll
  for (int o = 16; o > 0; o >>= 1) part += __shfl_xor(part, o);
  if (l == 0) red[r] = part;
  __syncthreads();
  float g = 1.f / (1.f + expf(-(red[r] + GB[0])));
  float4 y;
  y.x = g * x4.x + (1.f - g) * o0;
  y.y = g * x4.y + (1.f - g) * o1;
  y.z = g * x4.z + (1.f - g) * o2;
  y.w = g * x4.w + (1.f - g) * o3;
  *(float4*)&Y[(long)(baseRow + b * N + i0 + r) * DC + d0] = y;
}

// ---------------------------------------------------------------------------
// k_msg2v: msg = relu(t1 + max_j m2_j * ev_ij).  8 rows/block, 256 thr
// (32 dgrp x 8 rows).  grid (32, 8, 2): z=0 ligand (x<16), z=1 target.
// ---------------------------------------------------------------------------
__global__ __launch_bounds__(256) void k_msg2v(const float* __restrict__ T1,
                                               const float* __restrict__ M2,
                                               const float* __restrict__ EV,
                                               float* __restrict__ MSG) {
  int z = blockIdx.z, b = blockIdx.y;
  int Ni = z ? N2C : N1C, Nj = z ? N1C : N2C;
  if (blockIdx.x * 8 >= Ni) return;
  int t1off = z ? ROWS_L : 0, m2off = z ? 0 : ROWS_L;
  long ev_is = z ? 1L : (long)N2C, ev_js = z ? (long)N2C : 1L;
  int i0 = blockIdx.x * 8;
  __shared__ float m2s[32][DC + 4];
  __shared__ float evs[8][36];
  int dgrp = threadIdx.x & 31, row = threadIdx.x >> 5;
  int d0 = dgrp * 4;
  float a0 = -INFINITY, a1 = -INFINITY, a2 = -INFINITY, a3 = -INFINITY;
  const float* M2b = M2 + (long)(m2off + b * Nj) * DC;
  const float* EVb = EV + (long)b * (N1C * N2C);
  for (int j0 = 0; j0 < Nj; j0 += 32) {
    __syncthreads();
    for (int t = threadIdx.x; t < 32 * DC; t += 256)
      m2s[t >> 7][t & 127] = M2b[(long)(j0 + (t >> 7)) * DC + (t & 127)];
    for (int t = threadIdx.x; t < 256; t += 256)
      evs[t >> 5][t & 31] =
          EVb[(long)(i0 + (t >> 5)) * ev_is + (long)(j0 + (t & 31)) * ev_js];
    __syncthreads();
#pragma unroll 8
    for (int jj = 0; jj < 32; ++jj) {
      float4 m4 = *(const float4*)&m2s[jj][d0];
      float e = evs[row][jj];
      a0 = fmaxf(a0, m4.x * e);
      a1 = fmaxf(a1, m4.y * e);
      a2 = fmaxf(a2, m4.z * e);
      a3 = fmaxf(a3, m4.w * e);
    }
  }
  long grow = t1off + (long)b * Ni + i0 + row;
  float4 t4 = *(const float4*)&T1[grow * DC + d0];
  float4 o;
  o.x = fmaxf(t4.x + a0, 0.f);
  o.y = fmaxf(t4.y + a1, 0.f);
  o.z = fmaxf(t4.z + a2, 0.f);
  o.w = fmaxf(t4.w + a3, 0.f);
  *(float4*)&MSG[grow * DC + d0] = o;
}

// ---------------------------------------------------------------------------
// Fused GRU, 4 rows/block (768 blocks), 384 threads.  (Proven round-6/8
// version — the 8-row variant spilled: VGPR 28 < 16 live accumulators.)
// ---------------------------------------------------------------------------
__global__ __launch_bounds__(384) void k_gruf(
    const float* __restrict__ MSGp, const float* __restrict__ Hp,
    const float* __restrict__ WihT, const float* __restrict__ WhhT,
    const float* __restrict__ bih, const float* __restrict__ bhh,
    float* __restrict__ Y) {
  const int D = DC;
  int r0 = blockIdx.x * 4;
  __shared__ float xs_t[DC][4], hs_t[DC][4];
  __shared__ float gis[4][384], ghs[4][384];
  int tid = threadIdx.x;
  for (int t = tid; t < 4 * DC; t += 384) {
    int r = t >> 7, c = t & 127;
    xs_t[c][r] = MSGp[(long)(r0 + r) * D + c];
    hs_t[c][r] = Hp[(long)(r0 + r) * D + c];
  }
  __syncthreads();
  int dd = tid;  // 0..383
  float ai[4] = {0.f, 0.f, 0.f, 0.f}, ah[4] = {0.f, 0.f, 0.f, 0.f};
#pragma unroll 8
  for (int k = 0; k < DC; ++k) {
    float4 xv = *reinterpret_cast<const float4*>(&xs_t[k][0]);
    float4 hv = *reinterpret_cast<const float4*>(&hs_t[k][0]);
    float wi = WihT[(long)k * 384 + dd];
    float wh = WhhT[(long)k * 384 + dd];
    ai[0] = fmaf(xv.x, wi, ai[0]);
    ai[1] = fmaf(xv.y, wi, ai[1]);
    ai[2] = fmaf(xv.z, wi, ai[2]);
    ai[3] = fmaf(xv.w, wi, ai[3]);
    ah[0] = fmaf(hv.x, wh, ah[0]);
    ah[1] = fmaf(hv.y, wh, ah[1]);
    ah[2] = fmaf(hv.z, wh, ah[2]);
    ah[3] = fmaf(hv.w, wh, ah[3]);
  }
  float bi = bih[dd], bh = bhh[dd];
#pragma unroll
  for (int r = 0; r < 4; ++r) {
    gis[r][dd] = ai[r] + bi;
    ghs[r][dd] = ah[r] + bh;
  }
  __syncthreads();
  for (int t = tid; t < 4 * DC; t += 384) {
    int r = t >> 7, d = t & 127;
    float ir = gis[r][d], iz = gis[r][d + 128], inn = gis[r][d + 256];
    float hr = ghs[r][d], hz = ghs[r][d + 128], hn = ghs[r][d + 256];
    float rg = 1.f / (1.f + expf(-(ir + hr)));
    float zg = 1.f / (1.f + expf(-(iz + hz)));
    float ng = tanhf(inn + rg * hn);
    Y[(long)(r0 + r) * D + d] = (1.f - zg) * ng + zg * hs_t[d][r];
  }
}

// ---------------------------------------------------------------------------
// Pairwise physics + analytic grad/Hessian partials.  2 ligand atoms per
// block.  grid (64, 8), 256 threads (j).
// ---------------------------------------------------------------------------
__global__ __launch_bounds__(256) void k_pair(
    const float* __restrict__ UA, const float* __restrict__ VAT,
    const float* __restrict__ UB, const float* __restrict__ VBT,
    const float* __restrict__ AW2, const float* __restrict__ AB2,
    const float* __restrict__ BW2, const float* __restrict__ BB2,
    const float* __restrict__ LP, const float* __restrict__ TP,
    const float* __restrict__ LVDW, const float* __restrict__ TVDW,
    const float* __restrict__ LNM, const float* __restrict__ TNM,
    const float* __restrict__ II, const float* __restrict__ HBC,
    const float* __restrict__ HPC, float* __restrict__ PART) {
  const int D = DC, N1 = N1C, N2 = N2C;
  int i0 = blockIdx.x * 2, b = blockIdx.y, j = threadIdx.x;
  __shared__ float ua[2][128], ub[2][128], wa2[128], wb2[128];
  if (j < 128) {
    long rb = ((long)b * N1 + i0) * D + j;
    ua[0][j] = UA[rb];
    ub[0][j] = UB[rb];
    wa2[j] = AW2[j];
    wb2[j] = BW2[j];
  } else {
    int jj = j - 128;
    long rb = ((long)b * N1 + i0 + 1) * D + jj;
    ua[1][jj] = UA[rb];
    ub[1][jj] = UB[rb];
  }
  __syncthreads();
  const float* vat = VAT + (long)b * D * N2;
  const float* vbt = VBT + (long)b * D * N2;
  float dotA[2] = {0.f, 0.f}, dotB[2] = {0.f, 0.f};
#pragma unroll 4
  for (int d = 0; d < D; ++d) {
    float va = vat[(long)d * N2 + j];
    float vb = vbt[(long)d * N2 + j];
    dotA[0] += fmaxf(ua[0][d] + va, 0.f) * wa2[d];
    dotA[1] += fmaxf(ua[1][d] + va, 0.f) * wa2[d];
    dotB[0] += fmaxf(ub[0][d] + vb, 0.f) * wb2[d];
    dotB[1] += fmaxf(ub[1][d] + vb, 0.f) * wb2[d];
  }
  float hb2 = HBC[0] * HBC[0], hp2 = HPC[0] * HPC[0];
  float tx = TP[((long)b * N2 + j) * 3 + 0];
  float ty = TP[((long)b * N2 + j) * 3 + 1];
  float tz = TP[((long)b * N2 + j) * 3 + 2];
  float tvd = TVDW[b * N2 + j];
  float tnm = TNM[b * N2 + j];
  float res[2][8];
#pragma unroll
  for (int ii = 0; ii < 2; ++ii) {
    int i = i0 + ii;
    float A_raw = 1.f / (1.f + expf(-(dotA[ii] + AB2[0])));
    float A_vdw = A_raw * (0.0356f - 0.0178f) + 0.0178f;
    float B_raw = tanhf(dotB[ii] + BB2[0]) * 0.2f;

    float lx = LP[((long)b * N1 + i) * 3 + 0];
    float ly = LP[((long)b * N1 + i) * 3 + 1];
    float lz = LP[((long)b * N1 + i) * 3 + 2];
    float dx = lx - tx, dy = ly - ty, dz = lz - tz;
    float s2 = dx * dx + dy * dy + dz * dz + 1e-10f;
    float draw = sqrtf(s2);
    bool clamped = draw < 0.5f;
    float dmv = clamped ? 1e10f : draw;

    float dm0 = LVDW[b * N1 + i] + tvd + B_raw;
    float dm0c = (dm0 < 1e-4f) ? 1.f : dm0;
    float valid = LNM[b * N1 + i] * tnm;

    float rr = dm0c / dmv;
    float r2 = rr * rr, r6 = r2 * r2 * r2;
    float fv = r6 * r6 - 2.f * r6;
    float evdw = A_vdw * (fminf(fv, 100.f) * valid);

    float dmd = dmv - dm0;
    long ii0x = ((long)b * 3) * N1 * N2 + (long)i * N2 + j;
    float I0 = II[ii0x];
    float I1 = II[ii0x + (long)N1 * N2];
    float I2 = II[ii0x + 2L * N1 * N2];
    float u0 = dmd * I0 / (-0.7f);
    float u1 = dmd * I1 / (-0.7f);
    float vv = (1.5f - dmd) * I2;
    float ehb = fminf(fmaxf(u0, 0.f), 1.f) * (-hb2);
    float emt = fminf(fmaxf(u1, 0.f), 1.f) * (-hb2);
    float ehp = fminf(fmaxf(vv, 0.f), 1.f) * (-hp2);

    float gx = 0.f, gy = 0.f, gz = 0.f, d2t = 0.f;
    if (!clamped) {
      float Ep = 0.f, Epp = 0.f;
      if (fv < 100.f) {
        float c = A_vdw * valid;
        Ep += c * (-12.f) * r6 * (r6 - 1.f) / draw;
        Epp += c * r6 * (156.f * r6 - 84.f) / s2;
      }
      if (u0 > 0.f && u0 < 1.f) Ep += hb2 * I0 * (1.f / 0.7f);
      if (u1 > 0.f && u1 < 1.f) Ep += hb2 * I1 * (1.f / 0.7f);
      if (vv > 0.f && vv < 1.f) Ep += hp2 * I2;
      float invd = 1.f / draw;
      gx = Ep * dx * invd;
      gy = Ep * dy * invd;
      gz = Ep * dz * invd;
      float T = dx + dy + dz;
      float tt = T * T / s2;
      d2t = Epp * tt + Ep * (3.f - tt) * invd;
    }
    res[ii][0] = evdw;
    res[ii][1] = ehb;
    res[ii][2] = emt;
    res[ii][3] = ehp;
    res[ii][4] = gx;
    res[ii][5] = gy;
    res[ii][6] = gz;
    res[ii][7] = d2t;
  }
#pragma unroll
  for (int ii = 0; ii < 2; ++ii) {
    float o[8];
#pragma unroll
    for (int q = 0; q < 8; ++q) o[q] = blockSum(res[ii][q]);
    if (j == 0) {
      float* p = PART + ((long)b * N1 + i0 + ii) * 8;
#pragma unroll
      for (int q = 0; q < 8; ++q) p[q] = o[q];
    }
  }
}

// final deterministic reduction + output assembly (34 floats)
__global__ void k_final(const float* __restrict__ PART, const float* __restrict__ ROT,
                        const float* __restrict__ RC, float* __restrict__ OUT) {
  const int N1 = N1C;
  __shared__ float s[8][8];
  int t = threadIdx.x;
  if (t < 64) {
    int b = t >> 3, k1 = t & 7;
    float acc = 0.f;
    for (int i = 0; i < N1; ++i) acc += PART[((long)b * N1 + i) * 8 + k1];
    s[b][k1] = acc;
  }
  __syncthreads();
  if (t == 0) {
    float rcc = RC[0] * RC[0];
    float der1 = 0.f, der2 = 0.f;
    for (int b = 0; b < 8; ++b) {
      float w = 1.f / (1.f + rcc * ROT[b]);
      OUT[b * 4 + 0] = s[b][0] * w;
      OUT[b * 4 + 1] = s[b][1] * w;
      OUT[b * 4 + 2] = s[b][2] * w;
      OUT[b * 4 + 3] = s[b][3] * w;
      for (int c = 0; c < 3; ++c) {
        float S = s[b][4 + c] * w;
        der1 += S * S;
      }
      der2 += s[b][7] * w;
    }
    OUT[32] = der1 / 24.f;
    OUT[33] = -der2 / 8.f;
  }
}

// ---------------------------------------------------------------------------
// Host-side orchestration
// ---------------------------------------------------------------------------
extern "C" void kernel_launch(void* const* d_in, const int* in_sizes, int n_in,
                              void* d_out, int out_size, void* d_ws, size_t ws_size,
                              hipStream_t stream) {
  (void)in_sizes; (void)n_in; (void)out_size; (void)ws_size;
  const int D = DC;

  const float* ligand_h   = (const float*)d_in[0];
  const float* ligand_adj = (const float*)d_in[1];
  const float* target_h   = (const float*)d_in[2];
  const float* target_adj = (const float*)d_in[3];
  const float* inter_ind  = (const float*)d_in[4];
  const float* ligand_pos = (const float*)d_in[5];
  const float* target_pos = (const float*)d_in[6];
  const float* rotor      = (const float*)d_in[7];
  const float* lvdw       = (const float*)d_in[8];
  const float* tvdw       = (const float*)d_in[9];
  const float* lnm        = (const float*)d_in[12];
  const float* tnm        = (const float*)d_in[13];
  const float* emb_w      = (const float*)d_in[14];
  const float* gat_w      = (const float*)d_in[15];
  const float* gat_b      = (const float*)d_in[16];
  const float* gat_att    = (const float*)d_in[17];
  const float* gat_gate_w = (const float*)d_in[18];
  const float* gat_gate_b = (const float*)d_in[19];
  const float* int_wt_w   = (const float*)d_in[20];
  const float* int_wt_b   = (const float*)d_in[21];
  const float* int_mt_w   = (const float*)d_in[22];
  const float* int_mt_b   = (const float*)d_in[23];
  const float* gru_w_ih   = (const float*)d_in[24];
  const float* gru_w_hh   = (const float*)d_in[25];
  const float* gru_b_ih   = (const float*)d_in[26];
  const float* gru_b_hh   = (const float*)d_in[27];
  const float* A_w1       = (const float*)d_in[28];
  const float* A_b1       = (const float*)d_in[29];
  const float* A_w2       = (const float*)d_in[30];
  const float* A_b2       = (const float*)d_in[31];
  const float* B_w1       = (const float*)d_in[32];
  const float* B_b1       = (const float*)d_in[33];
  const float* B_w2       = (const float*)d_in[34];
  const float* B_b2       = (const float*)d_in[35];
  const float* hb_c       = (const float*)d_in[36];
  const float* hp_c       = (const float*)d_in[37];
  const float* rc_c       = (const float*)d_in[38];

  // workspace carve (floats)
  float* w = (float*)d_ws;
  auto take = [&](size_t n) { float* p = w; w += n; return p; };
  float* H0    = take((size_t)ROWS_ALL * DC);   // 393216
  float* H1    = take((size_t)ROWS_ALL * DC);
  float* NT    = take((size_t)ROWS_ALL * DC);
  float* E1    = take((size_t)ROWS_ALL * DC);
  float* EAL   = take((size_t)BB * N1C * N1C);  // 131072
  float* EAT   = take((size_t)BB * N2C * N2C);  // 524288
  float* ADJ12 = take((size_t)BB * N1C * N2C);  // 262144
  float* WA    = take((size_t)3 * DC * DC);     // 49152
  float* bA    = take((size_t)3 * DC);
  float* GIHT  = take((size_t)3 * DC * 384);    // 147456
  float* GHHT  = take((size_t)3 * DC * 384);
  float* PART  = take((size_t)BB * N1C * 8);
  // phase-disjoint aliases
  float* T1  = NT;
  float* M2  = E1;
  float* MSG = EAT;           // 393216 <= 524288
  float* UA  = EAL;           // 131072
  float* UB  = EAT;           // 131072 (front of EAT)
  float* VAT = NT;            // 262144 <= 393216
  float* VBT = E1;            // 262144

  // merged prep: adj12 + embedding + WA fuse + GRU weight transposes
  k_prep<<<2659, 256, 0, stream>>>(ligand_pos, target_pos, ADJ12, ligand_h,
                                   target_h, emb_w, H0, gat_w, gat_b, gat_att,
                                   WA, bA, gru_w_ih, gru_w_hh, GIHT, GHHT);

  float *cur = H0, *alt = H1;

  // GAT stack (3 layers)
  for (int l = 0; l < 3; ++l) {
    k_lin2h<<<ROWS_ALL / 8, 256, 0, stream>>>(
        cur, gat_w + (size_t)l * D * D, gat_b + l * D, WA + (size_t)l * D * D,
        bA + l * D, NT, E1, 1, 0);
    k_ea2<<<320, 256, 0, stream>>>(NT, E1, ligand_adj, target_adj, EAL, EAT);
    k_smagg3<<<dim3(N2C / 16, BB, 2), 512, 0, stream>>>(
        EAL, EAT, NT, cur, gat_gate_w + l * 2 * D, gat_gate_b + l, alt);
    float* t = cur; cur = alt; alt = t;
  }

  // interaction layers (both directions use OLD h)
  for (int l = 0; l < 3; ++l) {
    k_lin2h<<<ROWS_ALL / 8, 256, 0, stream>>>(
        cur, int_wt_w + (size_t)l * D * D, int_wt_b + l * D,
        int_mt_w + (size_t)l * D * D, int_mt_b + l * D, T1, M2, 1, 0);
    k_msg2v<<<dim3(32, 8, 2), 256, 0, stream>>>(T1, M2, ADJ12, MSG);
    k_gruf<<<ROWS_ALL / 4, 384, 0, stream>>>(MSG, cur, GIHT + (size_t)l * D * 384,
                                             GHHT + (size_t)l * D * 384,
                                             gru_b_ih + l * 384,
                                             gru_b_hh + l * 384, alt);
    float* t = cur; cur = alt; alt = t;
  }

  // pairwise feature precompute (U normal layout, V transposed [b][d][j])
  k_lin2h<<<ROWS_L / 8, 256, 0, stream>>>(cur, A_w1, A_b1, B_w1, B_b1, UA, UB,
                                          1, 0);
  k_lin2h<<<ROWS_T / 8, 256, 0, stream>>>(cur + (size_t)ROWS_L * DC,
                                          A_w1 + D * D, nullptr, B_w1 + D * D,
                                          nullptr, VAT, VBT, N2C, 1);

  // pairwise physics + analytic derivatives (2 atoms/block)
  k_pair<<<dim3(N1C / 2, BB), 256, 0, stream>>>(UA, VAT, UB, VBT, A_w2, A_b2,
                                                B_w2, B_b2, ligand_pos,
                                                target_pos, lvdw, tvdw, lnm,
                                                tnm, inter_ind, hb_c, hp_c,
                                                PART);

  // final reduction -> 34 outputs
  k_final<<<1, 256, 0, stream>>>(PART, rotor, rc_c, (float*)d_out);
}

// Round 11
// 330.983 us; speedup vs baseline: 1.3532x; 1.1221x over previous
//
#include <hip/hip_runtime.h>
#include <math.h>

// ---------------------------------------------------------------------------
// Problem constants (B=8, N1=128, N2=256, D=128, L=3, NH=54)
// Packed row space: rows 0..1023 = ligand (b*128+i), rows 1024..3071 = target
// (1024 + b*256 + j).
// ---------------------------------------------------------------------------
#define BB 8
#define N1C 128
#define N2C 256
#define DC 128
#define NHC 54
#define ROWS_L 1024
#define ROWS_T 2048
#define ROWS_ALL 3072

// ---------------------------------------------------------------------------
// Reductions (wave64)
// ---------------------------------------------------------------------------
__device__ __forceinline__ float wredSum(float v) {
#pragma unroll
  for (int o = 32; o > 0; o >>= 1) v += __shfl_down(v, o);
  return v;
}
__device__ float blockSum(float v) {
  __shared__ float red[9];
  v = wredSum(v);
  int lane = threadIdx.x & 63, wid = threadIdx.x >> 6;
  __syncthreads();
  if (lane == 0) red[wid] = v;
  __syncthreads();
  if (threadIdx.x == 0) {
    float s = 0.f;
    int nw = (blockDim.x + 63) >> 6;
    for (int i = 0; i < nw; ++i) s += red[i];
    red[8] = s;
  }
  __syncthreads();
  return red[8];
}

// ---------------------------------------------------------------------------
// k_prep: merged adj12 + embedding + GAT-weight-fuse + GRU-weight-transpose.
// grid = 1024 + 384 + 99 + 1152 = 2659 blocks, 256 threads.
// ---------------------------------------------------------------------------
__global__ __launch_bounds__(256) void k_prep(
    const float* __restrict__ LP, const float* __restrict__ TP,
    float* __restrict__ AD, const float* __restrict__ LH,
    const float* __restrict__ TH, const float* __restrict__ EW,
    float* __restrict__ H0, const float* __restrict__ GWp,
    const float* __restrict__ GBp, const float* __restrict__ ATT,
    float* __restrict__ WA, float* __restrict__ bA,
    const float* __restrict__ IH, const float* __restrict__ HH,
    float* __restrict__ GIHT, float* __restrict__ GHHT) {
  int bid = blockIdx.x, tid = threadIdx.x;
  if (bid < 1024) {  // ---- adj12 ----
    long idx = (long)bid * 256 + tid;
    int j = idx & (N2C - 1);
    long t = idx >> 8;
    int i = (int)(t & (N1C - 1));
    int b = (int)(t >> 7);
    float dx = LP[((long)b * N1C + i) * 3 + 0] - TP[((long)b * N2C + j) * 3 + 0];
    float dy = LP[((long)b * N1C + i) * 3 + 1] - TP[((long)b * N2C + j) * 3 + 1];
    float dz = LP[((long)b * N1C + i) * 3 + 2] - TP[((long)b * N2C + j) * 3 + 2];
    float d = sqrtf(dx * dx + dy * dy + dz * dz + 1e-10f);
    if (d < 0.5f) d = 1e10f;
    AD[idx] = (d <= 5.0f && d > 1e-3f) ? 1.f : 0.f;
  } else if (bid < 1024 + 384) {  // ---- embedding, 8 rows/block ----
    int r0 = (bid - 1024) * 8;
    __shared__ float xs[8][NHC];
    for (int t = tid; t < 8 * NHC; t += 256) {
      int rr = r0 + t / NHC, c = t % NHC;
      xs[t / NHC][c] = (rr < ROWS_L) ? LH[(long)rr * NHC + c]
                                     : TH[(long)(rr - ROWS_L) * NHC + c];
    }
    __syncthreads();
    int d = tid & 127, rb = (tid >> 7) * 4;
    float a[4] = {0.f, 0.f, 0.f, 0.f};
#pragma unroll 6
    for (int k = 0; k < NHC; ++k) {
      float wv = EW[(long)k * DC + d];
#pragma unroll
      for (int r = 0; r < 4; ++r) a[r] += xs[rb + r][k] * wv;
    }
#pragma unroll
    for (int r = 0; r < 4; ++r) H0[(long)(r0 + rb + r) * DC + d] = a[r];
  } else if (bid < 1024 + 384 + 99) {  // ---- wfuse: WA_l = W_l @ ATT_l ----
    int q = bid - 1408;
    int l = q / 33, bx = q % 33;
    const float* Wl = GWp + (long)l * DC * DC;
    const float* Al = ATT + (long)l * DC * DC;
    if (bx == 32) {
      if (tid < 128) {
        float acc = 0.f;
#pragma unroll 8
        for (int m = 0; m < DC; ++m)
          acc += GBp[l * DC + m] * Al[(long)m * DC + tid];
        bA[l * DC + tid] = acc;
      }
    } else {
      __shared__ float xs2[4][DC];
      int r0 = bx * 4;
      for (int t = tid; t < 4 * DC; t += 256)
        xs2[t >> 7][t & 127] = Wl[(long)r0 * DC + t];
      __syncthreads();
      if (tid < 128) {
        int d = tid;
        float a0 = 0.f, a1 = 0.f, a2 = 0.f, a3 = 0.f;
#pragma unroll 8
        for (int m = 0; m < DC; ++m) {
          float av = Al[(long)m * DC + d];
          a0 += xs2[0][m] * av;
          a1 += xs2[1][m] * av;
          a2 += xs2[2][m] * av;
          a3 += xs2[3][m] * av;
        }
        float* out = WA + (long)l * DC * DC + (long)r0 * DC + d;
        out[0] = a0;
        out[DC] = a1;
        out[2 * DC] = a2;
        out[3 * DC] = a3;
      }
    }
  } else {  // ---- GRU weight transposes ----
    long idx = (long)(bid - 1507) * 256 + tid;
    if (idx < 6L * 49152) {
      int a = (int)(idx / 49152);
      int rem = (int)(idx % 49152);
      int l = a >> 1, whh = a & 1;
      int c = rem / 384, rr = rem % 384;
      const float* src = (whh ? HH : IH) + (long)l * 49152;
      float* dst = (whh ? GHHT : GIHT) + (long)l * 49152;
      dst[(long)c * 384 + rr] = src[(long)rr * 128 + c];
    }
  }
}

// ---------------------------------------------------------------------------
// Dual-head linear (round-8 proven): Y1 = X@W1(+b1), Y2 = X@W2(+b2).
// 4 rows/block, 256 thr (tid>>7 = head, d = tid&127).  X staged TRANSPOSED.
// ---------------------------------------------------------------------------
__global__ __launch_bounds__(256) void k_lin2h(
    const float* __restrict__ X, const float* __restrict__ W1,
    const float* __restrict__ b1, const float* __restrict__ W2,
    const float* __restrict__ b2, float* __restrict__ Y1,
    float* __restrict__ Y2) {
  int r0 = blockIdx.x * 4;
  __shared__ float xs_t[DC][4];
  int tid = threadIdx.x;
  for (int t = tid; t < 4 * DC; t += 256) {
    int r = t >> 7, c = t & 127;
    xs_t[c][r] = X[(long)(r0 + r) * DC + c];
  }
  __syncthreads();
  int h = tid >> 7, d = tid & 127;
  const float* W = h ? W2 : W1;
  const float* bp = h ? b2 : b1;
  float* Y = h ? Y2 : Y1;
  float a0 = 0.f, a1 = 0.f, a2 = 0.f, a3 = 0.f;
#pragma unroll 8
  for (int k = 0; k < DC; ++k) {
    float4 xv = *(const float4*)&xs_t[k][0];
    float wv = W[(long)k * DC + d];
    a0 = fmaf(xv.x, wv, a0);
    a1 = fmaf(xv.y, wv, a1);
    a2 = fmaf(xv.z, wv, a2);
    a3 = fmaf(xv.w, wv, a3);
  }
  float bv = bp ? bp[d] : 0.f;
  Y[(long)(r0 + 0) * DC + d] = a0 + bv;
  Y[(long)(r0 + 1) * DC + d] = a1 + bv;
  Y[(long)(r0 + 2) * DC + d] = a2 + bv;
  Y[(long)(r0 + 3) * DC + d] = a3 + bv;
}

// ---------------------------------------------------------------------------
// k_featall: merged pairwise feature heads, one dispatch.  grid 768:
// bid<256 -> ligand rows (U layout, +bias), else target rows (V transposed
// [b][d][j], no bias).  tid>>7 selects head A/B.
// ---------------------------------------------------------------------------
__global__ __launch_bounds__(256) void k_featall(
    const float* __restrict__ X, const float* __restrict__ Aw1,
    const float* __restrict__ Ab1, const float* __restrict__ Bw1,
    const float* __restrict__ Bb1, float* __restrict__ UA,
    float* __restrict__ UB, float* __restrict__ VAT,
    float* __restrict__ VBT) {
  int bid = blockIdx.x;
  bool lig = bid < 256;
  int r0 = lig ? bid * 4 : ROWS_L + (bid - 256) * 4;
  __shared__ float xs_t[DC][4];
  int tid = threadIdx.x;
  for (int t = tid; t < 4 * DC; t += 256) {
    int r = t >> 7, c = t & 127;
    xs_t[c][r] = X[(long)(r0 + r) * DC + c];
  }
  __syncthreads();
  int h = tid >> 7, d = tid & 127;
  const float* W = (h ? Bw1 : Aw1) + (lig ? 0 : DC * DC);
  float a0 = 0.f, a1 = 0.f, a2 = 0.f, a3 = 0.f;
#pragma unroll 8
  for (int k = 0; k < DC; ++k) {
    float4 xv = *(const float4*)&xs_t[k][0];
    float wv = W[(long)k * DC + d];
    a0 = fmaf(xv.x, wv, a0);
    a1 = fmaf(xv.y, wv, a1);
    a2 = fmaf(xv.z, wv, a2);
    a3 = fmaf(xv.w, wv, a3);
  }
  if (lig) {
    float bv = h ? Bb1[d] : Ab1[d];
    float* Y = h ? UB : UA;
    Y[(long)(r0 + 0) * DC + d] = a0 + bv;
    Y[(long)(r0 + 1) * DC + d] = a1 + bv;
    Y[(long)(r0 + 2) * DC + d] = a2 + bv;
    Y[(long)(r0 + 3) * DC + d] = a3 + bv;
  } else {
    float* V = h ? VBT : VAT;
    int q = bid - 256;
    int b = q >> 6, rin = (q * 4) & 255;
    float* dst = &V[((long)b * DC + d) * N2C + rin];
    dst[0] = a0;
    dst[1] = a1;
    dst[2] = a2;
    dst[3] = a3;
  }
}

// ---------------------------------------------------------------------------
// k_ea2: ea[b,j,k] = e1_j.nt_k + nt_j.e1_k, masked by adjacency at write.
// Register-tiled: 32x64 tile, 256 thr, 2x4 outputs/thread.  Merged
// ligand+target: 64 + 256 = 320 blocks.
// ---------------------------------------------------------------------------
__global__ __launch_bounds__(256) void k_ea2(const float* __restrict__ NTp,
                                             const float* __restrict__ E1p,
                                             const float* __restrict__ ADJL,
                                             const float* __restrict__ ADJT,
                                             float* __restrict__ EAL,
                                             float* __restrict__ EAT) {
  int id = blockIdx.x;
  int N, base, j0, k0, b;
  const float* ADJ;
  float* EA;
  if (id < 64) {
    b = id >> 3;
    int rem = id & 7;
    N = N1C;
    base = b * N1C;
    j0 = (rem >> 1) * 32;
    k0 = (rem & 1) * 64;
    ADJ = ADJL + (long)b * N1C * N1C;
    EA = EAL + (long)b * N1C * N1C;
  } else {
    int q = id - 64;
    b = q >> 5;
    int rem = q & 31;
    N = N2C;
    base = ROWS_L + b * N2C;
    j0 = (rem >> 2) * 32;
    k0 = (rem & 3) * 64;
    ADJ = ADJT + (long)b * N2C * N2C;
    EA = EAT + (long)b * N2C * N2C;
  }
  __shared__ float aj_e1[32][34], aj_nt[32][34];
  __shared__ float bk_e1[32][68], bk_nt[32][68];
  int tid = threadIdx.x, tx = tid & 15, ty = tid >> 4;
  float acc[2][4];
#pragma unroll
  for (int r = 0; r < 2; ++r)
#pragma unroll
    for (int c = 0; c < 4; ++c) acc[r][c] = 0.f;
  for (int kc = 0; kc < DC; kc += 32) {
    __syncthreads();
    for (int t = tid; t < 1024; t += 256) {
      int kk = t & 31, rr = t >> 5;
      aj_e1[kk][rr] = E1p[(long)(base + j0 + rr) * DC + kc + kk];
      aj_nt[kk][rr] = NTp[(long)(base + j0 + rr) * DC + kc + kk];
    }
    for (int t = tid; t < 2048; t += 256) {
      int kk = t & 31, cc = t >> 5;
      bk_e1[kk][cc] = E1p[(long)(base + k0 + cc) * DC + kc + kk];
      bk_nt[kk][cc] = NTp[(long)(base + k0 + cc) * DC + kc + kk];
    }
    __syncthreads();
#pragma unroll
    for (int kk = 0; kk < 32; ++kk) {
      float2 ae = *(const float2*)&aj_e1[kk][ty * 2];
      float2 an = *(const float2*)&aj_nt[kk][ty * 2];
      float4 bn = *(const float4*)&bk_nt[kk][tx * 4];
      float4 be = *(const float4*)&bk_e1[kk][tx * 4];
      acc[0][0] = fmaf(ae.x, bn.x, fmaf(an.x, be.x, acc[0][0]));
      acc[0][1] = fmaf(ae.x, bn.y, fmaf(an.x, be.y, acc[0][1]));
      acc[0][2] = fmaf(ae.x, bn.z, fmaf(an.x, be.z, acc[0][2]));
      acc[0][3] = fmaf(ae.x, bn.w, fmaf(an.x, be.w, acc[0][3]));
      acc[1][0] = fmaf(ae.y, bn.x, fmaf(an.y, be.x, acc[1][0]));
      acc[1][1] = fmaf(ae.y, bn.y, fmaf(an.y, be.y, acc[1][1]));
      acc[1][2] = fmaf(ae.y, bn.z, fmaf(an.y, be.z, acc[1][2]));
      acc[1][3] = fmaf(ae.y, bn.w, fmaf(an.y, be.w, acc[1][3]));
    }
  }
#pragma unroll
  for (int r = 0; r < 2; ++r) {
    long rowi = (long)(j0 + ty * 2 + r) * N + k0 + tx * 4;
    float4 ad = *(const float4*)&ADJ[rowi];
    float4 o;
    o.x = (ad.x > 1e-6f) ? acc[r][0] : -9e15f;
    o.y = (ad.y > 1e-6f) ? acc[r][1] : -9e15f;
    o.z = (ad.z > 1e-6f) ? acc[r][2] : -9e15f;
    o.w = (ad.w > 1e-6f) ? acc[r][3] : -9e15f;
    *(float4*)&EA[rowi] = o;
  }
}

// ---------------------------------------------------------------------------
// k_smagg3: row-softmax + aggregate + gated residual.  16 rows/block,
// 512 threads (16 rowgrp x 32 dgrp x 4 cols).  grid (16, 8, 2).
// ---------------------------------------------------------------------------
__global__ __launch_bounds__(512) void k_smagg3(
    const float* __restrict__ EAL, const float* __restrict__ EAT,
    const float* __restrict__ NTp, const float* __restrict__ Xp,
    const float* __restrict__ GW, const float* __restrict__ GB,
    float* __restrict__ Y) {
  int z = blockIdx.z;
  int N = z ? N2C : N1C;
  if (blockIdx.x * 16 >= N) return;
  int ls = z ? 8 : 7;
  int baseRow = z ? ROWS_L : 0;
  const float* EA = z ? EAT : EAL;
  int b = blockIdx.y, i0 = blockIdx.x * 16;
  __shared__ float ps[16][N2C + 4];
  __shared__ float col[32][DC + 4];
  __shared__ float red[16];
  int tid = threadIdx.x;
  const float* EAb = EA + (long)b * N * N + (long)i0 * N;
  for (int t = tid; t < 16 * N; t += 512)
    ps[t >> ls][t & (N - 1)] = EAb[t];
  __syncthreads();
  int r = tid >> 5, l = tid & 31;  // 16 rows x 32 lanes
  {                                // softmax
    float m = -INFINITY;
    for (int k = l; k < N; k += 32) m = fmaxf(m, ps[r][k]);
#pragma unroll
    for (int o = 16; o > 0; o >>= 1) m = fmaxf(m, __shfl_xor(m, o));
    float s = 0.f;
    for (int k = l; k < N; k += 32) {
      float p = expf(ps[r][k] - m);
      ps[r][k] = p;
      s += p;
    }
#pragma unroll
    for (int o = 16; o > 0; o >>= 1) s += __shfl_xor(s, o);
    float inv = 1.f / s;
    for (int k = l; k < N; k += 32) ps[r][k] *= inv;
  }
  // aggregate: row r, cols d0..d0+3
  int d0 = l * 4;
  float a0 = 0.f, a1 = 0.f, a2 = 0.f, a3 = 0.f;
  const float* NTb = NTp + (long)(baseRow + b * N) * DC;
  for (int k0 = 0; k0 < N; k0 += 32) {
    __syncthreads();
    for (int t = tid; t < 32 * DC; t += 512)
      col[t >> 7][t & 127] = NTb[(long)(k0 + (t >> 7)) * DC + (t & 127)];
    __syncthreads();
#pragma unroll 8
    for (int kk = 0; kk < 32; ++kk) {
      float4 c4 = *(const float4*)&col[kk][d0];
      float p = ps[r][k0 + kk];
      a0 = fmaf(p, c4.x, a0);
      a1 = fmaf(p, c4.y, a1);
      a2 = fmaf(p, c4.z, a2);
      a3 = fmaf(p, c4.w, a3);
    }
  }
  // gate
  float4 gwd = *(const float4*)&GW[d0];
  float4 gwo = *(const float4*)&GW[DC + d0];
  float4 x4 = *(const float4*)&Xp[(long)(baseRow + b * N + i0 + r) * DC + d0];
  float o0 = fmaxf(a0, 0.f), o1 = fmaxf(a1, 0.f);
  float o2 = fmaxf(a2, 0.f), o3 = fmaxf(a3, 0.f);
  float part = x4.x * gwd.x + o0 * gwo.x + x4.y * gwd.y + o1 * gwo.y +
               x4.z * gwd.z + o2 * gwo.z + x4.w * gwd.w + o3 * gwo.w;
#pragma unroll
  for (int o = 16; o > 0; o >>= 1) part += __shfl_xor(part, o);
  if (l == 0) red[r] = part;
  __syncthreads();
  float g = 1.f / (1.f + expf(-(red[r] + GB[0])));
  float4 y;
  y.x = g * x4.x + (1.f - g) * o0;
  y.y = g * x4.y + (1.f - g) * o1;
  y.z = g * x4.z + (1.f - g) * o2;
  y.w = g * x4.w + (1.f - g) * o3;
  *(float4*)&Y[(long)(baseRow + b * N + i0 + r) * DC + d0] = y;
}

// ---------------------------------------------------------------------------
// k_msggru: fused msg + GRU.  4 packed rows per block, 512 threads.
// Phase A: msg[r][d] = relu(t1 + max_j m2_j[d]*ev[i,j]) -> xs_t (LDS).
// Phase B (tid<384): gi/gh GEMM (proven gruf inner loop), then combine.
// grid = ROWS_ALL/4 = 768 blocks.
// ---------------------------------------------------------------------------
__global__ __launch_bounds__(512) void k_msggru(
    const float* __restrict__ T1, const float* __restrict__ M2,
    const float* __restrict__ EV, const float* __restrict__ Hp,
    const float* __restrict__ WihT, const float* __restrict__ WhhT,
    const float* __restrict__ bih, const float* __restrict__ bhh,
    float* __restrict__ Y) {
  int r0 = blockIdx.x * 4;
  __shared__ float m2s[32][DC + 4];
  __shared__ float evs[4][36];
  __shared__ float xs_t[DC][4], hs_t[DC][4];
  __shared__ float gis[4][384], ghs[4][384];
  int tid = threadIdx.x;
  int Nj, m2base, b, i0in;
  long ev_is, ev_js;
  if (r0 < ROWS_L) {  // ligand update: msg over target atoms
    b = r0 >> 7;
    i0in = r0 & 127;
    Nj = N2C;
    m2base = ROWS_L + b * N2C;
    ev_is = N2C;
    ev_js = 1;
  } else {  // target update: msg over ligand atoms (transposed EV)
    int q = r0 - ROWS_L;
    b = q >> 8;
    i0in = q & 255;
    Nj = N1C;
    m2base = b * N1C;
    ev_is = 1;
    ev_js = N2C;
  }
  const float* EVb = EV + (long)b * (N1C * N2C);
  int r = tid >> 7, d = tid & 127;  // 4 rows x 128 d
  float acc = -INFINITY;
  for (int j0 = 0; j0 < Nj; j0 += 32) {
    __syncthreads();
    for (int t = tid; t < 32 * DC; t += 512)
      m2s[t >> 7][t & 127] = M2[(long)(m2base + j0 + (t >> 7)) * DC + (t & 127)];
    if (tid < 128)
      evs[tid >> 5][tid & 31] =
          EVb[(long)(i0in + (tid >> 5)) * ev_is + (long)(j0 + (tid & 31)) * ev_js];
    __syncthreads();
#pragma unroll 8
    for (int jj = 0; jj < 32; ++jj)
      acc = fmaxf(acc, m2s[jj][d] * evs[r][jj]);
  }
  xs_t[d][r] = fmaxf(T1[(long)(r0 + r) * DC + d] + acc, 0.f);
  for (int t = tid; t < 4 * DC; t += 512)
    hs_t[t & 127][t >> 7] = Hp[(long)(r0 + (t >> 7)) * DC + (t & 127)];
  __syncthreads();
  // Phase B: GRU matmul (proven k_gruf inner loop)
  if (tid < 384) {
    int dd = tid;
    float ai[4] = {0.f, 0.f, 0.f, 0.f}, ah[4] = {0.f, 0.f, 0.f, 0.f};
#pragma unroll 8
    for (int k = 0; k < DC; ++k) {
      float4 xv = *(const float4*)&xs_t[k][0];
      float4 hv = *(const float4*)&hs_t[k][0];
      float wi = WihT[(long)k * 384 + dd];
      float wh = WhhT[(long)k * 384 + dd];
      ai[0] = fmaf(xv.x, wi, ai[0]);
      ai[1] = fmaf(xv.y, wi, ai[1]);
      ai[2] = fmaf(xv.z, wi, ai[2]);
      ai[3] = fmaf(xv.w, wi, ai[3]);
      ah[0] = fmaf(hv.x, wh, ah[0]);
      ah[1] = fmaf(hv.y, wh, ah[1]);
      ah[2] = fmaf(hv.z, wh, ah[2]);
      ah[3] = fmaf(hv.w, wh, ah[3]);
    }
    float bi = bih[dd], bh = bhh[dd];
#pragma unroll
    for (int rr = 0; rr < 4; ++rr) {
      gis[rr][dd] = ai[rr] + bi;
      ghs[rr][dd] = ah[rr] + bh;
    }
  }
  __syncthreads();
  for (int t = tid; t < 4 * DC; t += 512) {
    int rr = t >> 7, dq = t & 127;
    float ir = gis[rr][dq], iz = gis[rr][dq + 128], inn = gis[rr][dq + 256];
    float hr = ghs[rr][dq], hz = ghs[rr][dq + 128], hn = ghs[rr][dq + 256];
    float rg = 1.f / (1.f + expf(-(ir + hr)));
    float zg = 1.f / (1.f + expf(-(iz + hz)));
    float ng = tanhf(inn + rg * hn);
    Y[(long)(r0 + rr) * DC + dq] = (1.f - zg) * ng + zg * hs_t[dq][rr];
  }
}

// ---------------------------------------------------------------------------
// Pairwise physics + analytic grad/Hessian partials.  2 ligand atoms per
// block.  grid (64, 8), 256 threads (j).
// ---------------------------------------------------------------------------
__global__ __launch_bounds__(256) void k_pair(
    const float* __restrict__ UA, const float* __restrict__ VAT,
    const float* __restrict__ UB, const float* __restrict__ VBT,
    const float* __restrict__ AW2, const float* __restrict__ AB2,
    const float* __restrict__ BW2, const float* __restrict__ BB2,
    const float* __restrict__ LP, const float* __restrict__ TP,
    const float* __restrict__ LVDW, const float* __restrict__ TVDW,
    const float* __restrict__ LNM, const float* __restrict__ TNM,
    const float* __restrict__ II, const float* __restrict__ HBC,
    const float* __restrict__ HPC, float* __restrict__ PART) {
  const int D = DC, N1 = N1C, N2 = N2C;
  int i0 = blockIdx.x * 2, b = blockIdx.y, j = threadIdx.x;
  __shared__ float ua[2][128], ub[2][128], wa2[128], wb2[128];
  if (j < 128) {
    long rb = ((long)b * N1 + i0) * D + j;
    ua[0][j] = UA[rb];
    ub[0][j] = UB[rb];
    wa2[j] = AW2[j];
    wb2[j] = BW2[j];
  } else {
    int jj = j - 128;
    long rb = ((long)b * N1 + i0 + 1) * D + jj;
    ua[1][jj] = UA[rb];
    ub[1][jj] = UB[rb];
  }
  __syncthreads();
  const float* vat = VAT + (long)b * D * N2;
  const float* vbt = VBT + (long)b * D * N2;
  float dotA[2] = {0.f, 0.f}, dotB[2] = {0.f, 0.f};
#pragma unroll 4
  for (int d = 0; d < D; ++d) {
    float va = vat[(long)d * N2 + j];
    float vb = vbt[(long)d * N2 + j];
    dotA[0] += fmaxf(ua[0][d] + va, 0.f) * wa2[d];
    dotA[1] += fmaxf(ua[1][d] + va, 0.f) * wa2[d];
    dotB[0] += fmaxf(ub[0][d] + vb, 0.f) * wb2[d];
    dotB[1] += fmaxf(ub[1][d] + vb, 0.f) * wb2[d];
  }
  float hb2 = HBC[0] * HBC[0], hp2 = HPC[0] * HPC[0];
  float tx = TP[((long)b * N2 + j) * 3 + 0];
  float ty = TP[((long)b * N2 + j) * 3 + 1];
  float tz = TP[((long)b * N2 + j) * 3 + 2];
  float tvd = TVDW[b * N2 + j];
  float tnm = TNM[b * N2 + j];
  float res[2][8];
#pragma unroll
  for (int ii = 0; ii < 2; ++ii) {
    int i = i0 + ii;
    float A_raw = 1.f / (1.f + expf(-(dotA[ii] + AB2[0])));
    float A_vdw = A_raw * (0.0356f - 0.0178f) + 0.0178f;
    float B_raw = tanhf(dotB[ii] + BB2[0]) * 0.2f;

    float lx = LP[((long)b * N1 + i) * 3 + 0];
    float ly = LP[((long)b * N1 + i) * 3 + 1];
    float lz = LP[((long)b * N1 + i) * 3 + 2];
    float dx = lx - tx, dy = ly - ty, dz = lz - tz;
    float s2 = dx * dx + dy * dy + dz * dz + 1e-10f;
    float draw = sqrtf(s2);
    bool clamped = draw < 0.5f;
    float dmv = clamped ? 1e10f : draw;

    float dm0 = LVDW[b * N1 + i] + tvd + B_raw;
    float dm0c = (dm0 < 1e-4f) ? 1.f : dm0;
    float valid = LNM[b * N1 + i] * tnm;

    float rr = dm0c / dmv;
    float r2 = rr * rr, r6 = r2 * r2 * r2;
    float fv = r6 * r6 - 2.f * r6;
    float evdw = A_vdw * (fminf(fv, 100.f) * valid);

    float dmd = dmv - dm0;
    long ii0x = ((long)b * 3) * N1 * N2 + (long)i * N2 + j;
    float I0 = II[ii0x];
    float I1 = II[ii0x + (long)N1 * N2];
    float I2 = II[ii0x + 2L * N1 * N2];
    float u0 = dmd * I0 / (-0.7f);
    float u1 = dmd * I1 / (-0.7f);
    float vv = (1.5f - dmd) * I2;
    float ehb = fminf(fmaxf(u0, 0.f), 1.f) * (-hb2);
    float emt = fminf(fmaxf(u1, 0.f), 1.f) * (-hb2);
    float ehp = fminf(fmaxf(vv, 0.f), 1.f) * (-hp2);

    float gx = 0.f, gy = 0.f, gz = 0.f, d2t = 0.f;
    if (!clamped) {
      float Ep = 0.f, Epp = 0.f;
      if (fv < 100.f) {
        float c = A_vdw * valid;
        Ep += c * (-12.f) * r6 * (r6 - 1.f) / draw;
        Epp += c * r6 * (156.f * r6 - 84.f) / s2;
      }
      if (u0 > 0.f && u0 < 1.f) Ep += hb2 * I0 * (1.f / 0.7f);
      if (u1 > 0.f && u1 < 1.f) Ep += hb2 * I1 * (1.f / 0.7f);
      if (vv > 0.f && vv < 1.f) Ep += hp2 * I2;
      float invd = 1.f / draw;
      gx = Ep * dx * invd;
      gy = Ep * dy * invd;
      gz = Ep * dz * invd;
      float T = dx + dy + dz;
      float tt = T * T / s2;
      d2t = Epp * tt + Ep * (3.f - tt) * invd;
    }
    res[ii][0] = evdw;
    res[ii][1] = ehb;
    res[ii][2] = emt;
    res[ii][3] = ehp;
    res[ii][4] = gx;
    res[ii][5] = gy;
    res[ii][6] = gz;
    res[ii][7] = d2t;
  }
#pragma unroll
  for (int ii = 0; ii < 2; ++ii) {
    float o[8];
#pragma unroll
    for (int q = 0; q < 8; ++q) o[q] = blockSum(res[ii][q]);
    if (j == 0) {
      float* p = PART + ((long)b * N1 + i0 + ii) * 8;
#pragma unroll
      for (int q = 0; q < 8; ++q) p[q] = o[q];
    }
  }
}

// final deterministic reduction + output assembly (34 floats)
__global__ void k_final(const float* __restrict__ PART, const float* __restrict__ ROT,
                        const float* __restrict__ RC, float* __restrict__ OUT) {
  const int N1 = N1C;
  __shared__ float s[8][8];
  int t = threadIdx.x;
  if (t < 64) {
    int b = t >> 3, k1 = t & 7;
    float acc = 0.f;
    for (int i = 0; i < N1; ++i) acc += PART[((long)b * N1 + i) * 8 + k1];
    s[b][k1] = acc;
  }
  __syncthreads();
  if (t == 0) {
    float rcc = RC[0] * RC[0];
    float der1 = 0.f, der2 = 0.f;
    for (int b = 0; b < 8; ++b) {
      float w = 1.f / (1.f + rcc * ROT[b]);
      OUT[b * 4 + 0] = s[b][0] * w;
      OUT[b * 4 + 1] = s[b][1] * w;
      OUT[b * 4 + 2] = s[b][2] * w;
      OUT[b * 4 + 3] = s[b][3] * w;
      for (int c = 0; c < 3; ++c) {
        float S = s[b][4 + c] * w;
        der1 += S * S;
      }
      der2 += s[b][7] * w;
    }
    OUT[32] = der1 / 24.f;
    OUT[33] = -der2 / 8.f;
  }
}

// ---------------------------------------------------------------------------
// Host-side orchestration
// ---------------------------------------------------------------------------
extern "C" void kernel_launch(void* const* d_in, const int* in_sizes, int n_in,
                              void* d_out, int out_size, void* d_ws, size_t ws_size,
                              hipStream_t stream) {
  (void)in_sizes; (void)n_in; (void)out_size; (void)ws_size;
  const int D = DC;

  const float* ligand_h   = (const float*)d_in[0];
  const float* ligand_adj = (const float*)d_in[1];
  const float* target_h   = (const float*)d_in[2];
  const float* target_adj = (const float*)d_in[3];
  const float* inter_ind  = (const float*)d_in[4];
  const float* ligand_pos = (const float*)d_in[5];
  const float* target_pos = (const float*)d_in[6];
  const float* rotor      = (const float*)d_in[7];
  const float* lvdw       = (const float*)d_in[8];
  const float* tvdw       = (const float*)d_in[9];
  const float* lnm        = (const float*)d_in[12];
  const float* tnm        = (const float*)d_in[13];
  const float* emb_w      = (const float*)d_in[14];
  const float* gat_w      = (const float*)d_in[15];
  const float* gat_b      = (const float*)d_in[16];
  const float* gat_att    = (const float*)d_in[17];
  const float* gat_gate_w = (const float*)d_in[18];
  const float* gat_gate_b = (const float*)d_in[19];
  const float* int_wt_w   = (const float*)d_in[20];
  const float* int_wt_b   = (const float*)d_in[21];
  const float* int_mt_w   = (const float*)d_in[22];
  const float* int_mt_b   = (const float*)d_in[23];
  const float* gru_w_ih   = (const float*)d_in[24];
  const float* gru_w_hh   = (const float*)d_in[25];
  const float* gru_b_ih   = (const float*)d_in[26];
  const float* gru_b_hh   = (const float*)d_in[27];
  const float* A_w1       = (const float*)d_in[28];
  const float* A_b1       = (const float*)d_in[29];
  const float* A_w2       = (const float*)d_in[30];
  const float* A_b2       = (const float*)d_in[31];
  const float* B_w1       = (const float*)d_in[32];
  const float* B_b1       = (const float*)d_in[33];
  const float* B_w2       = (const float*)d_in[34];
  const float* B_b2       = (const float*)d_in[35];
  const float* hb_c       = (const float*)d_in[36];
  const float* hp_c       = (const float*)d_in[37];
  const float* rc_c       = (const float*)d_in[38];

  // workspace carve (floats)
  float* w = (float*)d_ws;
  auto take = [&](size_t n) { float* p = w; w += n; return p; };
  float* H0    = take((size_t)ROWS_ALL * DC);   // 393216
  float* H1    = take((size_t)ROWS_ALL * DC);
  float* NT    = take((size_t)ROWS_ALL * DC);
  float* E1    = take((size_t)ROWS_ALL * DC);
  float* EAL   = take((size_t)BB * N1C * N1C);  // 131072
  float* EAT   = take((size_t)BB * N2C * N2C);  // 524288
  float* ADJ12 = take((size_t)BB * N1C * N2C);  // 262144
  float* WA    = take((size_t)3 * DC * DC);     // 49152
  float* bA    = take((size_t)3 * DC);
  float* GIHT  = take((size_t)3 * DC * 384);    // 147456
  float* GHHT  = take((size_t)3 * DC * 384);
  float* PART  = take((size_t)BB * N1C * 8);
  // phase-disjoint aliases
  float* T1  = NT;
  float* M2  = E1;
  float* UA  = EAL;           // 131072
  float* UB  = EAT;           // 131072 (front of EAT)
  float* VAT = NT;            // 262144 <= 393216
  float* VBT = E1;            // 262144

  // merged prep: adj12 + embedding + WA fuse + GRU weight transposes
  k_prep<<<2659, 256, 0, stream>>>(ligand_pos, target_pos, ADJ12, ligand_h,
                                   target_h, emb_w, H0, gat_w, gat_b, gat_att,
                                   WA, bA, gru_w_ih, gru_w_hh, GIHT, GHHT);

  float *cur = H0, *alt = H1;

  // GAT stack (3 layers)
  for (int l = 0; l < 3; ++l) {
    k_lin2h<<<ROWS_ALL / 4, 256, 0, stream>>>(
        cur, gat_w + (size_t)l * D * D, gat_b + l * D, WA + (size_t)l * D * D,
        bA + l * D, NT, E1);
    k_ea2<<<320, 256, 0, stream>>>(NT, E1, ligand_adj, target_adj, EAL, EAT);
    k_smagg3<<<dim3(N2C / 16, BB, 2), 512, 0, stream>>>(
        EAL, EAT, NT, cur, gat_gate_w + l * 2 * D, gat_gate_b + l, alt);
    float* t = cur; cur = alt; alt = t;
  }

  // interaction layers (both directions use OLD h; msg+gru fused)
  for (int l = 0; l < 3; ++l) {
    k_lin2h<<<ROWS_ALL / 4, 256, 0, stream>>>(
        cur, int_wt_w + (size_t)l * D * D, int_wt_b + l * D,
        int_mt_w + (size_t)l * D * D, int_mt_b + l * D, T1, M2);
    k_msggru<<<ROWS_ALL / 4, 512, 0, stream>>>(
        T1, M2, ADJ12, cur, GIHT + (size_t)l * D * 384,
        GHHT + (size_t)l * D * 384, gru_b_ih + l * 384, gru_b_hh + l * 384,
        alt);
    float* t = cur; cur = alt; alt = t;
  }

  // pairwise feature heads, single dispatch (U normal, V transposed [b][d][j])
  k_featall<<<768, 256, 0, stream>>>(cur, A_w1, A_b1, B_w1, B_b1, UA, UB, VAT,
                                     VBT);

  // pairwise physics + analytic derivatives (2 atoms/block)
  k_pair<<<dim3(N1C / 2, BB), 256, 0, stream>>>(UA, VAT, UB, VBT, A_w2, A_b2,
                                                B_w2, B_b2, ligand_pos,
                                                target_pos, lvdw, tvdw, lnm,
                                                tnm, inter_ind, hb_c, hp_c,
                                                PART);

  // final reduction -> 34 outputs
  k_final<<<1, 256, 0, stream>>>(PART, rotor, rc_c, (float*)d_out);
}

// Round 12
// 310.044 us; speedup vs baseline: 1.4446x; 1.0675x over previous
//
#include <hip/hip_runtime.h>
#include <math.h>

// ---------------------------------------------------------------------------
// Problem constants (B=8, N1=128, N2=256, D=128, L=3, NH=54)
// Packed row space: rows 0..1023 = ligand (b*128+i), rows 1024..3071 = target
// (1024 + b*256 + j).
// ---------------------------------------------------------------------------
#define BB 8
#define N1C 128
#define N2C 256
#define DC 128
#define NHC 54
#define ROWS_L 1024
#define ROWS_T 2048
#define ROWS_ALL 3072

// ---------------------------------------------------------------------------
// Reductions (wave64)
// ---------------------------------------------------------------------------
__device__ __forceinline__ float wredSum(float v) {
#pragma unroll
  for (int o = 32; o > 0; o >>= 1) v += __shfl_down(v, o);
  return v;
}
__device__ float blockSum(float v) {
  __shared__ float red[9];
  v = wredSum(v);
  int lane = threadIdx.x & 63, wid = threadIdx.x >> 6;
  __syncthreads();
  if (lane == 0) red[wid] = v;
  __syncthreads();
  if (threadIdx.x == 0) {
    float s = 0.f;
    int nw = (blockDim.x + 63) >> 6;
    for (int i = 0; i < nw; ++i) s += red[i];
    red[8] = s;
  }
  __syncthreads();
  return red[8];
}

// ---------------------------------------------------------------------------
// k_prep: merged adj12 + embedding + GAT-weight-fuse + GRU-weight-transpose.
// grid = 1024 + 384 + 99 + 1152 = 2659 blocks, 256 threads.
// ---------------------------------------------------------------------------
__global__ __launch_bounds__(256) void k_prep(
    const float* __restrict__ LP, const float* __restrict__ TP,
    float* __restrict__ AD, const float* __restrict__ LH,
    const float* __restrict__ TH, const float* __restrict__ EW,
    float* __restrict__ H0, const float* __restrict__ GWp,
    const float* __restrict__ GBp, const float* __restrict__ ATT,
    float* __restrict__ WA, float* __restrict__ bA,
    const float* __restrict__ IH, const float* __restrict__ HH,
    float* __restrict__ GIHT, float* __restrict__ GHHT) {
  int bid = blockIdx.x, tid = threadIdx.x;
  if (bid < 1024) {  // ---- adj12 ----
    long idx = (long)bid * 256 + tid;
    int j = idx & (N2C - 1);
    long t = idx >> 8;
    int i = (int)(t & (N1C - 1));
    int b = (int)(t >> 7);
    float dx = LP[((long)b * N1C + i) * 3 + 0] - TP[((long)b * N2C + j) * 3 + 0];
    float dy = LP[((long)b * N1C + i) * 3 + 1] - TP[((long)b * N2C + j) * 3 + 1];
    float dz = LP[((long)b * N1C + i) * 3 + 2] - TP[((long)b * N2C + j) * 3 + 2];
    float d = sqrtf(dx * dx + dy * dy + dz * dz + 1e-10f);
    if (d < 0.5f) d = 1e10f;
    AD[idx] = (d <= 5.0f && d > 1e-3f) ? 1.f : 0.f;
  } else if (bid < 1024 + 384) {  // ---- embedding, 8 rows/block ----
    int r0 = (bid - 1024) * 8;
    __shared__ float xs[8][NHC];
    for (int t = tid; t < 8 * NHC; t += 256) {
      int rr = r0 + t / NHC, c = t % NHC;
      xs[t / NHC][c] = (rr < ROWS_L) ? LH[(long)rr * NHC + c]
                                     : TH[(long)(rr - ROWS_L) * NHC + c];
    }
    __syncthreads();
    int d = tid & 127, rb = (tid >> 7) * 4;
    float a[4] = {0.f, 0.f, 0.f, 0.f};
#pragma unroll 6
    for (int k = 0; k < NHC; ++k) {
      float wv = EW[(long)k * DC + d];
#pragma unroll
      for (int r = 0; r < 4; ++r) a[r] += xs[rb + r][k] * wv;
    }
#pragma unroll
    for (int r = 0; r < 4; ++r) H0[(long)(r0 + rb + r) * DC + d] = a[r];
  } else if (bid < 1024 + 384 + 99) {  // ---- wfuse: WA_l = W_l @ ATT_l ----
    int q = bid - 1408;
    int l = q / 33, bx = q % 33;
    const float* Wl = GWp + (long)l * DC * DC;
    const float* Al = ATT + (long)l * DC * DC;
    if (bx == 32) {
      if (tid < 128) {
        float acc = 0.f;
#pragma unroll 8
        for (int m = 0; m < DC; ++m)
          acc += GBp[l * DC + m] * Al[(long)m * DC + tid];
        bA[l * DC + tid] = acc;
      }
    } else {
      __shared__ float xs2[4][DC];
      int r0 = bx * 4;
      for (int t = tid; t < 4 * DC; t += 256)
        xs2[t >> 7][t & 127] = Wl[(long)r0 * DC + t];
      __syncthreads();
      if (tid < 128) {
        int d = tid;
        float a0 = 0.f, a1 = 0.f, a2 = 0.f, a3 = 0.f;
#pragma unroll 8
        for (int m = 0; m < DC; ++m) {
          float av = Al[(long)m * DC + d];
          a0 += xs2[0][m] * av;
          a1 += xs2[1][m] * av;
          a2 += xs2[2][m] * av;
          a3 += xs2[3][m] * av;
        }
        float* out = WA + (long)l * DC * DC + (long)r0 * DC + d;
        out[0] = a0;
        out[DC] = a1;
        out[2 * DC] = a2;
        out[3 * DC] = a3;
      }
    }
  } else {  // ---- GRU weight transposes ----
    long idx = (long)(bid - 1507) * 256 + tid;
    if (idx < 6L * 49152) {
      int a = (int)(idx / 49152);
      int rem = (int)(idx % 49152);
      int l = a >> 1, whh = a & 1;
      int c = rem / 384, rr = rem % 384;
      const float* src = (whh ? HH : IH) + (long)l * 49152;
      float* dst = (whh ? GHHT : GIHT) + (long)l * 49152;
      dst[(long)c * 384 + rr] = src[(long)rr * 128 + c];
    }
  }
}

// ---------------------------------------------------------------------------
// Dual-head linear (round-8 proven): Y1 = X@W1(+b1), Y2 = X@W2(+b2).
// 4 rows/block, 256 thr (tid>>7 = head, d = tid&127).  X staged TRANSPOSED.
// ---------------------------------------------------------------------------
__global__ __launch_bounds__(256) void k_lin2h(
    const float* __restrict__ X, const float* __restrict__ W1,
    const float* __restrict__ b1, const float* __restrict__ W2,
    const float* __restrict__ b2, float* __restrict__ Y1,
    float* __restrict__ Y2) {
  int r0 = blockIdx.x * 4;
  __shared__ float xs_t[DC][4];
  int tid = threadIdx.x;
  for (int t = tid; t < 4 * DC; t += 256) {
    int r = t >> 7, c = t & 127;
    xs_t[c][r] = X[(long)(r0 + r) * DC + c];
  }
  __syncthreads();
  int h = tid >> 7, d = tid & 127;
  const float* W = h ? W2 : W1;
  const float* bp = h ? b2 : b1;
  float* Y = h ? Y2 : Y1;
  float a0 = 0.f, a1 = 0.f, a2 = 0.f, a3 = 0.f;
#pragma unroll 8
  for (int k = 0; k < DC; ++k) {
    float4 xv = *(const float4*)&xs_t[k][0];
    float wv = W[(long)k * DC + d];
    a0 = fmaf(xv.x, wv, a0);
    a1 = fmaf(xv.y, wv, a1);
    a2 = fmaf(xv.z, wv, a2);
    a3 = fmaf(xv.w, wv, a3);
  }
  float bv = bp ? bp[d] : 0.f;
  Y[(long)(r0 + 0) * DC + d] = a0 + bv;
  Y[(long)(r0 + 1) * DC + d] = a1 + bv;
  Y[(long)(r0 + 2) * DC + d] = a2 + bv;
  Y[(long)(r0 + 3) * DC + d] = a3 + bv;
}

// ---------------------------------------------------------------------------
// k_featall: merged pairwise feature heads, one dispatch.  grid 768:
// bid<256 -> ligand rows (U layout, +bias), else target rows (V transposed
// [b][d][j], no bias).  tid>>7 selects head A/B.
// ---------------------------------------------------------------------------
__global__ __launch_bounds__(256) void k_featall(
    const float* __restrict__ X, const float* __restrict__ Aw1,
    const float* __restrict__ Ab1, const float* __restrict__ Bw1,
    const float* __restrict__ Bb1, float* __restrict__ UA,
    float* __restrict__ UB, float* __restrict__ VAT,
    float* __restrict__ VBT) {
  int bid = blockIdx.x;
  bool lig = bid < 256;
  int r0 = lig ? bid * 4 : ROWS_L + (bid - 256) * 4;
  __shared__ float xs_t[DC][4];
  int tid = threadIdx.x;
  for (int t = tid; t < 4 * DC; t += 256) {
    int r = t >> 7, c = t & 127;
    xs_t[c][r] = X[(long)(r0 + r) * DC + c];
  }
  __syncthreads();
  int h = tid >> 7, d = tid & 127;
  const float* W = (h ? Bw1 : Aw1) + (lig ? 0 : DC * DC);
  float a0 = 0.f, a1 = 0.f, a2 = 0.f, a3 = 0.f;
#pragma unroll 8
  for (int k = 0; k < DC; ++k) {
    float4 xv = *(const float4*)&xs_t[k][0];
    float wv = W[(long)k * DC + d];
    a0 = fmaf(xv.x, wv, a0);
    a1 = fmaf(xv.y, wv, a1);
    a2 = fmaf(xv.z, wv, a2);
    a3 = fmaf(xv.w, wv, a3);
  }
  if (lig) {
    float bv = h ? Bb1[d] : Ab1[d];
    float* Y = h ? UB : UA;
    Y[(long)(r0 + 0) * DC + d] = a0 + bv;
    Y[(long)(r0 + 1) * DC + d] = a1 + bv;
    Y[(long)(r0 + 2) * DC + d] = a2 + bv;
    Y[(long)(r0 + 3) * DC + d] = a3 + bv;
  } else {
    float* V = h ? VBT : VAT;
    int q = bid - 256;
    int b = q >> 6, rin = (q * 4) & 255;
    float* dst = &V[((long)b * DC + d) * N2C + rin];
    dst[0] = a0;
    dst[1] = a1;
    dst[2] = a2;
    dst[3] = a3;
  }
}

// ---------------------------------------------------------------------------
// k_ea2: ea[b,j,k] = e1_j.nt_k + nt_j.e1_k, masked by adjacency at write.
// Register-tiled: 32x64 tile, 256 thr, 2x4 outputs/thread.  Merged
// ligand+target: 64 + 256 = 320 blocks.
// ---------------------------------------------------------------------------
__global__ __launch_bounds__(256) void k_ea2(const float* __restrict__ NTp,
                                             const float* __restrict__ E1p,
                                             const float* __restrict__ ADJL,
                                             const float* __restrict__ ADJT,
                                             float* __restrict__ EAL,
                                             float* __restrict__ EAT) {
  int id = blockIdx.x;
  int N, base, j0, k0, b;
  const float* ADJ;
  float* EA;
  if (id < 64) {
    b = id >> 3;
    int rem = id & 7;
    N = N1C;
    base = b * N1C;
    j0 = (rem >> 1) * 32;
    k0 = (rem & 1) * 64;
    ADJ = ADJL + (long)b * N1C * N1C;
    EA = EAL + (long)b * N1C * N1C;
  } else {
    int q = id - 64;
    b = q >> 5;
    int rem = q & 31;
    N = N2C;
    base = ROWS_L + b * N2C;
    j0 = (rem >> 2) * 32;
    k0 = (rem & 3) * 64;
    ADJ = ADJT + (long)b * N2C * N2C;
    EA = EAT + (long)b * N2C * N2C;
  }
  __shared__ float aj_e1[32][34], aj_nt[32][34];
  __shared__ float bk_e1[32][68], bk_nt[32][68];
  int tid = threadIdx.x, tx = tid & 15, ty = tid >> 4;
  float acc[2][4];
#pragma unroll
  for (int r = 0; r < 2; ++r)
#pragma unroll
    for (int c = 0; c < 4; ++c) acc[r][c] = 0.f;
  for (int kc = 0; kc < DC; kc += 32) {
    __syncthreads();
    for (int t = tid; t < 1024; t += 256) {
      int kk = t & 31, rr = t >> 5;
      aj_e1[kk][rr] = E1p[(long)(base + j0 + rr) * DC + kc + kk];
      aj_nt[kk][rr] = NTp[(long)(base + j0 + rr) * DC + kc + kk];
    }
    for (int t = tid; t < 2048; t += 256) {
      int kk = t & 31, cc = t >> 5;
      bk_e1[kk][cc] = E1p[(long)(base + k0 + cc) * DC + kc + kk];
      bk_nt[kk][cc] = NTp[(long)(base + k0 + cc) * DC + kc + kk];
    }
    __syncthreads();
#pragma unroll
    for (int kk = 0; kk < 32; ++kk) {
      float2 ae = *(const float2*)&aj_e1[kk][ty * 2];
      float2 an = *(const float2*)&aj_nt[kk][ty * 2];
      float4 bn = *(const float4*)&bk_nt[kk][tx * 4];
      float4 be = *(const float4*)&bk_e1[kk][tx * 4];
      acc[0][0] = fmaf(ae.x, bn.x, fmaf(an.x, be.x, acc[0][0]));
      acc[0][1] = fmaf(ae.x, bn.y, fmaf(an.x, be.y, acc[0][1]));
      acc[0][2] = fmaf(ae.x, bn.z, fmaf(an.x, be.z, acc[0][2]));
      acc[0][3] = fmaf(ae.x, bn.w, fmaf(an.x, be.w, acc[0][3]));
      acc[1][0] = fmaf(ae.y, bn.x, fmaf(an.y, be.x, acc[1][0]));
      acc[1][1] = fmaf(ae.y, bn.y, fmaf(an.y, be.y, acc[1][1]));
      acc[1][2] = fmaf(ae.y, bn.z, fmaf(an.y, be.z, acc[1][2]));
      acc[1][3] = fmaf(ae.y, bn.w, fmaf(an.y, be.w, acc[1][3]));
    }
  }
#pragma unroll
  for (int r = 0; r < 2; ++r) {
    long rowi = (long)(j0 + ty * 2 + r) * N + k0 + tx * 4;
    float4 ad = *(const float4*)&ADJ[rowi];
    float4 o;
    o.x = (ad.x > 1e-6f) ? acc[r][0] : -9e15f;
    o.y = (ad.y > 1e-6f) ? acc[r][1] : -9e15f;
    o.z = (ad.z > 1e-6f) ? acc[r][2] : -9e15f;
    o.w = (ad.w > 1e-6f) ? acc[r][3] : -9e15f;
    *(float4*)&EA[rowi] = o;
  }
}

// ---------------------------------------------------------------------------
// k_smagg3: row-softmax + aggregate + gated residual.  16 rows/block,
// 512 threads (16 rowgrp x 32 dgrp x 4 cols).  grid (16, 8, 2).
// ---------------------------------------------------------------------------
__global__ __launch_bounds__(512) void k_smagg3(
    const float* __restrict__ EAL, const float* __restrict__ EAT,
    const float* __restrict__ NTp, const float* __restrict__ Xp,
    const float* __restrict__ GW, const float* __restrict__ GB,
    float* __restrict__ Y) {
  int z = blockIdx.z;
  int N = z ? N2C : N1C;
  if (blockIdx.x * 16 >= N) return;
  int ls = z ? 8 : 7;
  int baseRow = z ? ROWS_L : 0;
  const float* EA = z ? EAT : EAL;
  int b = blockIdx.y, i0 = blockIdx.x * 16;
  __shared__ float ps[16][N2C + 4];
  __shared__ float col[32][DC + 4];
  __shared__ float red[16];
  int tid = threadIdx.x;
  const float* EAb = EA + (long)b * N * N + (long)i0 * N;
  for (int t = tid; t < 16 * N; t += 512)
    ps[t >> ls][t & (N - 1)] = EAb[t];
  __syncthreads();
  int r = tid >> 5, l = tid & 31;  // 16 rows x 32 lanes
  {                                // softmax
    float m = -INFINITY;
    for (int k = l; k < N; k += 32) m = fmaxf(m, ps[r][k]);
#pragma unroll
    for (int o = 16; o > 0; o >>= 1) m = fmaxf(m, __shfl_xor(m, o));
    float s = 0.f;
    for (int k = l; k < N; k += 32) {
      float p = expf(ps[r][k] - m);
      ps[r][k] = p;
      s += p;
    }
#pragma unroll
    for (int o = 16; o > 0; o >>= 1) s += __shfl_xor(s, o);
    float inv = 1.f / s;
    for (int k = l; k < N; k += 32) ps[r][k] *= inv;
  }
  // aggregate: row r, cols d0..d0+3
  int d0 = l * 4;
  float a0 = 0.f, a1 = 0.f, a2 = 0.f, a3 = 0.f;
  const float* NTb = NTp + (long)(baseRow + b * N) * DC;
  for (int k0 = 0; k0 < N; k0 += 32) {
    __syncthreads();
    for (int t = tid; t < 32 * DC; t += 512)
      col[t >> 7][t & 127] = NTb[(long)(k0 + (t >> 7)) * DC + (t & 127)];
    __syncthreads();
#pragma unroll 8
    for (int kk = 0; kk < 32; ++kk) {
      float4 c4 = *(const float4*)&col[kk][d0];
      float p = ps[r][k0 + kk];
      a0 = fmaf(p, c4.x, a0);
      a1 = fmaf(p, c4.y, a1);
      a2 = fmaf(p, c4.z, a2);
      a3 = fmaf(p, c4.w, a3);
    }
  }
  // gate
  float4 gwd = *(const float4*)&GW[d0];
  float4 gwo = *(const float4*)&GW[DC + d0];
  float4 x4 = *(const float4*)&Xp[(long)(baseRow + b * N + i0 + r) * DC + d0];
  float o0 = fmaxf(a0, 0.f), o1 = fmaxf(a1, 0.f);
  float o2 = fmaxf(a2, 0.f), o3 = fmaxf(a3, 0.f);
  float part = x4.x * gwd.x + o0 * gwo.x + x4.y * gwd.y + o1 * gwo.y +
               x4.z * gwd.z + o2 * gwo.z + x4.w * gwd.w + o3 * gwo.w;
#pragma unroll
  for (int o = 16; o > 0; o >>= 1) part += __shfl_xor(part, o);
  if (l == 0) red[r] = part;
  __syncthreads();
  float g = 1.f / (1.f + expf(-(red[r] + GB[0])));
  float4 y;
  y.x = g * x4.x + (1.f - g) * o0;
  y.y = g * x4.y + (1.f - g) * o1;
  y.z = g * x4.z + (1.f - g) * o2;
  y.w = g * x4.w + (1.f - g) * o3;
  *(float4*)&Y[(long)(baseRow + b * N + i0 + r) * DC + d0] = y;
}

// ---------------------------------------------------------------------------
// k_msggru: fused msg + GRU.  8 packed rows per block, 512 threads,
// grid = ROWS_ALL/8 = 384 blocks.
// Phase A: msg[r][d] = relu(t1 + max_j m2_j[d]*ev[i,j]) -> xs_t (LDS);
//          each thread handles rows (tid>>7) and (tid>>7)+4.
// Phase B (tid<384): gi/gh GEMM as TWO sequential 4-row passes (the proven
//          4-accumulator loop; #pragma unroll 1 prevents the 16-acc spill).
// LDS pool union: phase A {m2s, evs} <-> phase B {gis, ghs}.
// ---------------------------------------------------------------------------
__global__ __launch_bounds__(512) void k_msggru(
    const float* __restrict__ T1, const float* __restrict__ M2,
    const float* __restrict__ EV, const float* __restrict__ Hp,
    const float* __restrict__ WihT, const float* __restrict__ WhhT,
    const float* __restrict__ bih, const float* __restrict__ bhh,
    float* __restrict__ Y) {
  int r0 = blockIdx.x * 8;
  __shared__ float pool[6144];  // A: m2s[32][132] (4224) + evs[8][36] (288)
                                // B: gis[8][384] (3072) + ghs[8][384] (3072)
  __shared__ float xs_t[DC][8], hs_t[DC][8];
  float* m2s = pool;            // [32][132]
  float* evs = pool + 4224;     // [8][36]
  float* gis = pool;            // [8][384]
  float* ghs = pool + 3072;
  int tid = threadIdx.x;
  int Nj, m2base, b, i0in, ntile;
  long ev_is, ev_js;
  if (r0 < ROWS_L) {  // ligand update: msg over target atoms
    b = r0 >> 7;
    i0in = r0 & 127;
    Nj = N2C;
    ntile = N2C / 32;
    m2base = ROWS_L + b * N2C;
    ev_is = N2C;
    ev_js = 1;
  } else {  // target update: msg over ligand atoms (transposed EV)
    int q = r0 - ROWS_L;
    b = q >> 8;
    i0in = q & 255;
    Nj = N1C;
    ntile = N1C / 32;
    m2base = b * N1C;
    ev_is = 1;
    ev_js = N2C;
  }
  (void)Nj;
  const float* EVb = EV + (long)b * (N1C * N2C);
  int r = tid >> 7, d = tid & 127;  // rows r and r+4, col d
  float acc0 = -INFINITY, acc1 = -INFINITY;
  for (int jt = 0; jt < ntile; ++jt) {
    int j0 = jt * 32;
    __syncthreads();
    for (int t = tid; t < 32 * DC; t += 512)
      m2s[(t >> 7) * 132 + (t & 127)] =
          M2[(long)(m2base + j0 + (t >> 7)) * DC + (t & 127)];
    if (tid < 256)
      evs[(tid >> 5) * 36 + (tid & 31)] =
          EVb[(long)(i0in + (tid >> 5)) * ev_is +
              (long)(j0 + (tid & 31)) * ev_js];
    __syncthreads();
#pragma unroll 8
    for (int jj = 0; jj < 32; ++jj) {
      float m = m2s[jj * 132 + d];
      acc0 = fmaxf(acc0, m * evs[r * 36 + jj]);
      acc1 = fmaxf(acc1, m * evs[(r + 4) * 36 + jj]);
    }
  }
  xs_t[d][r] = fmaxf(T1[(long)(r0 + r) * DC + d] + acc0, 0.f);
  xs_t[d][r + 4] = fmaxf(T1[(long)(r0 + r + 4) * DC + d] + acc1, 0.f);
  for (int t = tid; t < 8 * DC; t += 512)
    hs_t[t & 127][t >> 7] = Hp[(long)(r0 + (t >> 7)) * DC + (t & 127)];
  __syncthreads();
  // Phase B: two 4-row GEMM passes (proven inner loop)
  if (tid < 384) {
    int dd = tid;
    float bi = bih[dd], bh = bhh[dd];
#pragma unroll 1
    for (int pass = 0; pass < 2; ++pass) {
      int rb = pass * 4;
      float ai[4] = {0.f, 0.f, 0.f, 0.f}, ah[4] = {0.f, 0.f, 0.f, 0.f};
#pragma unroll 8
      for (int k = 0; k < DC; ++k) {
        float4 xv = *(const float4*)&xs_t[k][rb];
        float4 hv = *(const float4*)&hs_t[k][rb];
        float wi = WihT[(long)k * 384 + dd];
        float wh = WhhT[(long)k * 384 + dd];
        ai[0] = fmaf(xv.x, wi, ai[0]);
        ai[1] = fmaf(xv.y, wi, ai[1]);
        ai[2] = fmaf(xv.z, wi, ai[2]);
        ai[3] = fmaf(xv.w, wi, ai[3]);
        ah[0] = fmaf(hv.x, wh, ah[0]);
        ah[1] = fmaf(hv.y, wh, ah[1]);
        ah[2] = fmaf(hv.z, wh, ah[2]);
        ah[3] = fmaf(hv.w, wh, ah[3]);
      }
#pragma unroll
      for (int rr = 0; rr < 4; ++rr) {
        gis[(rb + rr) * 384 + dd] = ai[rr] + bi;
        ghs[(rb + rr) * 384 + dd] = ah[rr] + bh;
      }
    }
  }
  __syncthreads();
  for (int t = tid; t < 8 * DC; t += 512) {
    int rr = t >> 7, dq = t & 127;
    float ir = gis[rr * 384 + dq], iz = gis[rr * 384 + dq + 128],
          inn = gis[rr * 384 + dq + 256];
    float hr = ghs[rr * 384 + dq], hz = ghs[rr * 384 + dq + 128],
          hn = ghs[rr * 384 + dq + 256];
    float rg = 1.f / (1.f + expf(-(ir + hr)));
    float zg = 1.f / (1.f + expf(-(iz + hz)));
    float ng = tanhf(inn + rg * hn);
    Y[(long)(r0 + rr) * DC + dq] = (1.f - zg) * ng + zg * hs_t[dq][rr];
  }
}

// ---------------------------------------------------------------------------
// Pairwise physics + analytic grad/Hessian partials.  2 ligand atoms per
// block.  grid (64, 8), 256 threads (j).
// ---------------------------------------------------------------------------
__global__ __launch_bounds__(256) void k_pair(
    const float* __restrict__ UA, const float* __restrict__ VAT,
    const float* __restrict__ UB, const float* __restrict__ VBT,
    const float* __restrict__ AW2, const float* __restrict__ AB2,
    const float* __restrict__ BW2, const float* __restrict__ BB2,
    const float* __restrict__ LP, const float* __restrict__ TP,
    const float* __restrict__ LVDW, const float* __restrict__ TVDW,
    const float* __restrict__ LNM, const float* __restrict__ TNM,
    const float* __restrict__ II, const float* __restrict__ HBC,
    const float* __restrict__ HPC, float* __restrict__ PART) {
  const int D = DC, N1 = N1C, N2 = N2C;
  int i0 = blockIdx.x * 2, b = blockIdx.y, j = threadIdx.x;
  __shared__ float ua[2][128], ub[2][128], wa2[128], wb2[128];
  if (j < 128) {
    long rb = ((long)b * N1 + i0) * D + j;
    ua[0][j] = UA[rb];
    ub[0][j] = UB[rb];
    wa2[j] = AW2[j];
    wb2[j] = BW2[j];
  } else {
    int jj = j - 128;
    long rb = ((long)b * N1 + i0 + 1) * D + jj;
    ua[1][jj] = UA[rb];
    ub[1][jj] = UB[rb];
  }
  __syncthreads();
  const float* vat = VAT + (long)b * D * N2;
  const float* vbt = VBT + (long)b * D * N2;
  float dotA[2] = {0.f, 0.f}, dotB[2] = {0.f, 0.f};
#pragma unroll 4
  for (int d = 0; d < D; ++d) {
    float va = vat[(long)d * N2 + j];
    float vb = vbt[(long)d * N2 + j];
    dotA[0] += fmaxf(ua[0][d] + va, 0.f) * wa2[d];
    dotA[1] += fmaxf(ua[1][d] + va, 0.f) * wa2[d];
    dotB[0] += fmaxf(ub[0][d] + vb, 0.f) * wb2[d];
    dotB[1] += fmaxf(ub[1][d] + vb, 0.f) * wb2[d];
  }
  float hb2 = HBC[0] * HBC[0], hp2 = HPC[0] * HPC[0];
  float tx = TP[((long)b * N2 + j) * 3 + 0];
  float ty = TP[((long)b * N2 + j) * 3 + 1];
  float tz = TP[((long)b * N2 + j) * 3 + 2];
  float tvd = TVDW[b * N2 + j];
  float tnm = TNM[b * N2 + j];
  float res[2][8];
#pragma unroll
  for (int ii = 0; ii < 2; ++ii) {
    int i = i0 + ii;
    float A_raw = 1.f / (1.f + expf(-(dotA[ii] + AB2[0])));
    float A_vdw = A_raw * (0.0356f - 0.0178f) + 0.0178f;
    float B_raw = tanhf(dotB[ii] + BB2[0]) * 0.2f;

    float lx = LP[((long)b * N1 + i) * 3 + 0];
    float ly = LP[((long)b * N1 + i) * 3 + 1];
    float lz = LP[((long)b * N1 + i) * 3 + 2];
    float dx = lx - tx, dy = ly - ty, dz = lz - tz;
    float s2 = dx * dx + dy * dy + dz * dz + 1e-10f;
    float draw = sqrtf(s2);
    bool clamped = draw < 0.5f;
    float dmv = clamped ? 1e10f : draw;

    float dm0 = LVDW[b * N1 + i] + tvd + B_raw;
    float dm0c = (dm0 < 1e-4f) ? 1.f : dm0;
    float valid = LNM[b * N1 + i] * tnm;

    float rr = dm0c / dmv;
    float r2 = rr * rr, r6 = r2 * r2 * r2;
    float fv = r6 * r6 - 2.f * r6;
    float evdw = A_vdw * (fminf(fv, 100.f) * valid);

    float dmd = dmv - dm0;
    long ii0x = ((long)b * 3) * N1 * N2 + (long)i * N2 + j;
    float I0 = II[ii0x];
    float I1 = II[ii0x + (long)N1 * N2];
    float I2 = II[ii0x + 2L * N1 * N2];
    float u0 = dmd * I0 / (-0.7f);
    float u1 = dmd * I1 / (-0.7f);
    float vv = (1.5f - dmd) * I2;
    float ehb = fminf(fmaxf(u0, 0.f), 1.f) * (-hb2);
    float emt = fminf(fmaxf(u1, 0.f), 1.f) * (-hb2);
    float ehp = fminf(fmaxf(vv, 0.f), 1.f) * (-hp2);

    float gx = 0.f, gy = 0.f, gz = 0.f, d2t = 0.f;
    if (!clamped) {
      float Ep = 0.f, Epp = 0.f;
      if (fv < 100.f) {
        float c = A_vdw * valid;
        Ep += c * (-12.f) * r6 * (r6 - 1.f) / draw;
        Epp += c * r6 * (156.f * r6 - 84.f) / s2;
      }
      if (u0 > 0.f && u0 < 1.f) Ep += hb2 * I0 * (1.f / 0.7f);
      if (u1 > 0.f && u1 < 1.f) Ep += hb2 * I1 * (1.f / 0.7f);
      if (vv > 0.f && vv < 1.f) Ep += hp2 * I2;
      float invd = 1.f / draw;
      gx = Ep * dx * invd;
      gy = Ep * dy * invd;
      gz = Ep * dz * invd;
      float T = dx + dy + dz;
      float tt = T * T / s2;
      d2t = Epp * tt + Ep * (3.f - tt) * invd;
    }
    res[ii][0] = evdw;
    res[ii][1] = ehb;
    res[ii][2] = emt;
    res[ii][3] = ehp;
    res[ii][4] = gx;
    res[ii][5] = gy;
    res[ii][6] = gz;
    res[ii][7] = d2t;
  }
#pragma unroll
  for (int ii = 0; ii < 2; ++ii) {
    float o[8];
#pragma unroll
    for (int q = 0; q < 8; ++q) o[q] = blockSum(res[ii][q]);
    if (j == 0) {
      float* p = PART + ((long)b * N1 + i0 + ii) * 8;
#pragma unroll
      for (int q = 0; q < 8; ++q) p[q] = o[q];
    }
  }
}

// final deterministic reduction + output assembly (34 floats)
__global__ void k_final(const float* __restrict__ PART, const float* __restrict__ ROT,
                        const float* __restrict__ RC, float* __restrict__ OUT) {
  const int N1 = N1C;
  __shared__ float s[8][8];
  int t = threadIdx.x;
  if (t < 64) {
    int b = t >> 3, k1 = t & 7;
    float acc = 0.f;
    for (int i = 0; i < N1; ++i) acc += PART[((long)b * N1 + i) * 8 + k1];
    s[b][k1] = acc;
  }
  __syncthreads();
  if (t == 0) {
    float rcc = RC[0] * RC[0];
    float der1 = 0.f, der2 = 0.f;
    for (int b = 0; b < 8; ++b) {
      float w = 1.f / (1.f + rcc * ROT[b]);
      OUT[b * 4 + 0] = s[b][0] * w;
      OUT[b * 4 + 1] = s[b][1] * w;
      OUT[b * 4 + 2] = s[b][2] * w;
      OUT[b * 4 + 3] = s[b][3] * w;
      for (int c = 0; c < 3; ++c) {
        float S = s[b][4 + c] * w;
        der1 += S * S;
      }
      der2 += s[b][7] * w;
    }
    OUT[32] = der1 / 24.f;
    OUT[33] = -der2 / 8.f;
  }
}

// ---------------------------------------------------------------------------
// Host-side orchestration
// ---------------------------------------------------------------------------
extern "C" void kernel_launch(void* const* d_in, const int* in_sizes, int n_in,
                              void* d_out, int out_size, void* d_ws, size_t ws_size,
                              hipStream_t stream) {
  (void)in_sizes; (void)n_in; (void)out_size; (void)ws_size;
  const int D = DC;

  const float* ligand_h   = (const float*)d_in[0];
  const float* ligand_adj = (const float*)d_in[1];
  const float* target_h   = (const float*)d_in[2];
  const float* target_adj = (const float*)d_in[3];
  const float* inter_ind  = (const float*)d_in[4];
  const float* ligand_pos = (const float*)d_in[5];
  const float* target_pos = (const float*)d_in[6];
  const float* rotor      = (const float*)d_in[7];
  const float* lvdw       = (const float*)d_in[8];
  const float* tvdw       = (const float*)d_in[9];
  const float* lnm        = (const float*)d_in[12];
  const float* tnm        = (const float*)d_in[13];
  const float* emb_w      = (const float*)d_in[14];
  const float* gat_w      = (const float*)d_in[15];
  const float* gat_b      = (const float*)d_in[16];
  const float* gat_att    = (const float*)d_in[17];
  const float* gat_gate_w = (const float*)d_in[18];
  const float* gat_gate_b = (const float*)d_in[19];
  const float* int_wt_w   = (const float*)d_in[20];
  const float* int_wt_b   = (const float*)d_in[21];
  const float* int_mt_w   = (const float*)d_in[22];
  const float* int_mt_b   = (const float*)d_in[23];
  const float* gru_w_ih   = (const float*)d_in[24];
  const float* gru_w_hh   = (const float*)d_in[25];
  const float* gru_b_ih   = (const float*)d_in[26];
  const float* gru_b_hh   = (const float*)d_in[27];
  const float* A_w1       = (const float*)d_in[28];
  const float* A_b1       = (const float*)d_in[29];
  const float* A_w2       = (const float*)d_in[30];
  const float* A_b2       = (const float*)d_in[31];
  const float* B_w1       = (const float*)d_in[32];
  const float* B_b1       = (const float*)d_in[33];
  const float* B_w2       = (const float*)d_in[34];
  const float* B_b2       = (const float*)d_in[35];
  const float* hb_c       = (const float*)d_in[36];
  const float* hp_c       = (const float*)d_in[37];
  const float* rc_c       = (const float*)d_in[38];

  // workspace carve (floats)
  float* w = (float*)d_ws;
  auto take = [&](size_t n) { float* p = w; w += n; return p; };
  float* H0    = take((size_t)ROWS_ALL * DC);   // 393216
  float* H1    = take((size_t)ROWS_ALL * DC);
  float* NT    = take((size_t)ROWS_ALL * DC);
  float* E1    = take((size_t)ROWS_ALL * DC);
  float* EAL   = take((size_t)BB * N1C * N1C);  // 131072
  float* EAT   = take((size_t)BB * N2C * N2C);  // 524288
  float* ADJ12 = take((size_t)BB * N1C * N2C);  // 262144
  float* WA    = take((size_t)3 * DC * DC);     // 49152
  float* bA    = take((size_t)3 * DC);
  float* GIHT  = take((size_t)3 * DC * 384);    // 147456
  float* GHHT  = take((size_t)3 * DC * 384);
  float* PART  = take((size_t)BB * N1C * 8);
  // phase-disjoint aliases
  float* T1  = NT;
  float* M2  = E1;
  float* UA  = EAL;           // 131072
  float* UB  = EAT;           // 131072 (front of EAT)
  float* VAT = NT;            // 262144 <= 393216
  float* VBT = E1;            // 262144

  // merged prep: adj12 + embedding + WA fuse + GRU weight transposes
  k_prep<<<2659, 256, 0, stream>>>(ligand_pos, target_pos, ADJ12, ligand_h,
                                   target_h, emb_w, H0, gat_w, gat_b, gat_att,
                                   WA, bA, gru_w_ih, gru_w_hh, GIHT, GHHT);

  float *cur = H0, *alt = H1;

  // GAT stack (3 layers)
  for (int l = 0; l < 3; ++l) {
    k_lin2h<<<ROWS_ALL / 4, 256, 0, stream>>>(
        cur, gat_w + (size_t)l * D * D, gat_b + l * D, WA + (size_t)l * D * D,
        bA + l * D, NT, E1);
    k_ea2<<<320, 256, 0, stream>>>(NT, E1, ligand_adj, target_adj, EAL, EAT);
    k_smagg3<<<dim3(N2C / 16, BB, 2), 512, 0, stream>>>(
        EAL, EAT, NT, cur, gat_gate_w + l * 2 * D, gat_gate_b + l, alt);
    float* t = cur; cur = alt; alt = t;
  }

  // interaction layers (both directions use OLD h; msg+gru fused, 8 rows)
  for (int l = 0; l < 3; ++l) {
    k_lin2h<<<ROWS_ALL / 4, 256, 0, stream>>>(
        cur, int_wt_w + (size_t)l * D * D, int_wt_b + l * D,
        int_mt_w + (size_t)l * D * D, int_mt_b + l * D, T1, M2);
    k_msggru<<<ROWS_ALL / 8, 512, 0, stream>>>(
        T1, M2, ADJ12, cur, GIHT + (size_t)l * D * 384,
        GHHT + (size_t)l * D * 384, gru_b_ih + l * 384, gru_b_hh + l * 384,
        alt);
    float* t = cur; cur = alt; alt = t;
  }

  // pairwise feature heads, single dispatch (U normal, V transposed [b][d][j])
  k_featall<<<768, 256, 0, stream>>>(cur, A_w1, A_b1, B_w1, B_b1, UA, UB, VAT,
                                     VBT);

  // pairwise physics + analytic derivatives (2 atoms/block)
  k_pair<<<dim3(N1C / 2, BB), 256, 0, stream>>>(UA, VAT, UB, VBT, A_w2, A_b2,
                                                B_w2, B_b2, ligand_pos,
                                                target_pos, lvdw, tvdw, lnm,
                                                tnm, inter_ind, hb_c, hp_c,
                                                PART);

  // final reduction -> 34 outputs
  k_final<<<1, 256, 0, stream>>>(PART, rotor, rc_c, (float*)d_out);
}

// Round 13
// 308.255 us; speedup vs baseline: 1.4530x; 1.0058x over previous
//
#include <hip/hip_runtime.h>
#include <math.h>

// ---------------------------------------------------------------------------
// Problem constants (B=8, N1=128, N2=256, D=128, L=3, NH=54)
// Packed row space: rows 0..1023 = ligand (b*128+i), rows 1024..3071 = target
// (1024 + b*256 + j).
// ---------------------------------------------------------------------------
#define BB 8
#define N1C 128
#define N2C 256
#define DC 128
#define NHC 54
#define ROWS_L 1024
#define ROWS_T 2048
#define ROWS_ALL 3072

// ---------------------------------------------------------------------------
// Reductions (wave64)
// ---------------------------------------------------------------------------
__device__ __forceinline__ float wredSum(float v) {
#pragma unroll
  for (int o = 32; o > 0; o >>= 1) v += __shfl_down(v, o);
  return v;
}
__device__ float blockSum(float v) {
  __shared__ float red[9];
  v = wredSum(v);
  int lane = threadIdx.x & 63, wid = threadIdx.x >> 6;
  __syncthreads();
  if (lane == 0) red[wid] = v;
  __syncthreads();
  if (threadIdx.x == 0) {
    float s = 0.f;
    int nw = (blockDim.x + 63) >> 6;
    for (int i = 0; i < nw; ++i) s += red[i];
    red[8] = s;
  }
  __syncthreads();
  return red[8];
}

// ---------------------------------------------------------------------------
// k_prep: merged adj12 + embedding + GAT-weight-fuse + GRU-weight-transpose.
// grid = 1024 + 384 + 99 + 1152 = 2659 blocks, 256 threads.
// ---------------------------------------------------------------------------
__global__ __launch_bounds__(256) void k_prep(
    const float* __restrict__ LP, const float* __restrict__ TP,
    float* __restrict__ AD, const float* __restrict__ LH,
    const float* __restrict__ TH, const float* __restrict__ EW,
    float* __restrict__ H0, const float* __restrict__ GWp,
    const float* __restrict__ GBp, const float* __restrict__ ATT,
    float* __restrict__ WA, float* __restrict__ bA,
    const float* __restrict__ IH, const float* __restrict__ HH,
    float* __restrict__ GIHT, float* __restrict__ GHHT) {
  int bid = blockIdx.x, tid = threadIdx.x;
  if (bid < 1024) {  // ---- adj12 ----
    long idx = (long)bid * 256 + tid;
    int j = idx & (N2C - 1);
    long t = idx >> 8;
    int i = (int)(t & (N1C - 1));
    int b = (int)(t >> 7);
    float dx = LP[((long)b * N1C + i) * 3 + 0] - TP[((long)b * N2C + j) * 3 + 0];
    float dy = LP[((long)b * N1C + i) * 3 + 1] - TP[((long)b * N2C + j) * 3 + 1];
    float dz = LP[((long)b * N1C + i) * 3 + 2] - TP[((long)b * N2C + j) * 3 + 2];
    float d = sqrtf(dx * dx + dy * dy + dz * dz + 1e-10f);
    if (d < 0.5f) d = 1e10f;
    AD[idx] = (d <= 5.0f && d > 1e-3f) ? 1.f : 0.f;
  } else if (bid < 1024 + 384) {  // ---- embedding, 8 rows/block ----
    int r0 = (bid - 1024) * 8;
    __shared__ float xs[8][NHC];
    for (int t = tid; t < 8 * NHC; t += 256) {
      int rr = r0 + t / NHC, c = t % NHC;
      xs[t / NHC][c] = (rr < ROWS_L) ? LH[(long)rr * NHC + c]
                                     : TH[(long)(rr - ROWS_L) * NHC + c];
    }
    __syncthreads();
    int d = tid & 127, rb = (tid >> 7) * 4;
    float a[4] = {0.f, 0.f, 0.f, 0.f};
#pragma unroll 6
    for (int k = 0; k < NHC; ++k) {
      float wv = EW[(long)k * DC + d];
#pragma unroll
      for (int r = 0; r < 4; ++r) a[r] += xs[rb + r][k] * wv;
    }
#pragma unroll
    for (int r = 0; r < 4; ++r) H0[(long)(r0 + rb + r) * DC + d] = a[r];
  } else if (bid < 1024 + 384 + 99) {  // ---- wfuse: WA_l = W_l @ ATT_l ----
    int q = bid - 1408;
    int l = q / 33, bx = q % 33;
    const float* Wl = GWp + (long)l * DC * DC;
    const float* Al = ATT + (long)l * DC * DC;
    if (bx == 32) {
      if (tid < 128) {
        float acc = 0.f;
#pragma unroll 8
        for (int m = 0; m < DC; ++m)
          acc += GBp[l * DC + m] * Al[(long)m * DC + tid];
        bA[l * DC + tid] = acc;
      }
    } else {
      __shared__ float xs2[4][DC];
      int r0 = bx * 4;
      for (int t = tid; t < 4 * DC; t += 256)
        xs2[t >> 7][t & 127] = Wl[(long)r0 * DC + t];
      __syncthreads();
      if (tid < 128) {
        int d = tid;
        float a0 = 0.f, a1 = 0.f, a2 = 0.f, a3 = 0.f;
#pragma unroll 8
        for (int m = 0; m < DC; ++m) {
          float av = Al[(long)m * DC + d];
          a0 += xs2[0][m] * av;
          a1 += xs2[1][m] * av;
          a2 += xs2[2][m] * av;
          a3 += xs2[3][m] * av;
        }
        float* out = WA + (long)l * DC * DC + (long)r0 * DC + d;
        out[0] = a0;
        out[DC] = a1;
        out[2 * DC] = a2;
        out[3 * DC] = a3;
      }
    }
  } else {  // ---- GRU weight transposes ----
    long idx = (long)(bid - 1507) * 256 + tid;
    if (idx < 6L * 49152) {
      int a = (int)(idx / 49152);
      int rem = (int)(idx % 49152);
      int l = a >> 1, whh = a & 1;
      int c = rem / 384, rr = rem % 384;
      const float* src = (whh ? HH : IH) + (long)l * 49152;
      float* dst = (whh ? GHHT : GIHT) + (long)l * 49152;
      dst[(long)c * 384 + rr] = src[(long)rr * 128 + c];
    }
  }
}

// ---------------------------------------------------------------------------
// Dual-head linear (round-8 proven): Y1 = X@W1(+b1), Y2 = X@W2(+b2).
// 4 rows/block, 256 thr (tid>>7 = head, d = tid&127).  X staged TRANSPOSED.
// ---------------------------------------------------------------------------
__global__ __launch_bounds__(256) void k_lin2h(
    const float* __restrict__ X, const float* __restrict__ W1,
    const float* __restrict__ b1, const float* __restrict__ W2,
    const float* __restrict__ b2, float* __restrict__ Y1,
    float* __restrict__ Y2) {
  int r0 = blockIdx.x * 4;
  __shared__ float xs_t[DC][4];
  int tid = threadIdx.x;
  for (int t = tid; t < 4 * DC; t += 256) {
    int r = t >> 7, c = t & 127;
    xs_t[c][r] = X[(long)(r0 + r) * DC + c];
  }
  __syncthreads();
  int h = tid >> 7, d = tid & 127;
  const float* W = h ? W2 : W1;
  const float* bp = h ? b2 : b1;
  float* Y = h ? Y2 : Y1;
  float a0 = 0.f, a1 = 0.f, a2 = 0.f, a3 = 0.f;
#pragma unroll 8
  for (int k = 0; k < DC; ++k) {
    float4 xv = *(const float4*)&xs_t[k][0];
    float wv = W[(long)k * DC + d];
    a0 = fmaf(xv.x, wv, a0);
    a1 = fmaf(xv.y, wv, a1);
    a2 = fmaf(xv.z, wv, a2);
    a3 = fmaf(xv.w, wv, a3);
  }
  float bv = bp ? bp[d] : 0.f;
  Y[(long)(r0 + 0) * DC + d] = a0 + bv;
  Y[(long)(r0 + 1) * DC + d] = a1 + bv;
  Y[(long)(r0 + 2) * DC + d] = a2 + bv;
  Y[(long)(r0 + 3) * DC + d] = a3 + bv;
}

// ---------------------------------------------------------------------------
// k_featall: merged pairwise feature heads, one dispatch.  grid 768:
// bid<256 -> ligand rows (U layout, +bias), else target rows (V transposed
// [b][d][j], no bias).  tid>>7 selects head A/B.
// ---------------------------------------------------------------------------
__global__ __launch_bounds__(256) void k_featall(
    const float* __restrict__ X, const float* __restrict__ Aw1,
    const float* __restrict__ Ab1, const float* __restrict__ Bw1,
    const float* __restrict__ Bb1, float* __restrict__ UA,
    float* __restrict__ UB, float* __restrict__ VAT,
    float* __restrict__ VBT) {
  int bid = blockIdx.x;
  bool lig = bid < 256;
  int r0 = lig ? bid * 4 : ROWS_L + (bid - 256) * 4;
  __shared__ float xs_t[DC][4];
  int tid = threadIdx.x;
  for (int t = tid; t < 4 * DC; t += 256) {
    int r = t >> 7, c = t & 127;
    xs_t[c][r] = X[(long)(r0 + r) * DC + c];
  }
  __syncthreads();
  int h = tid >> 7, d = tid & 127;
  const float* W = (h ? Bw1 : Aw1) + (lig ? 0 : DC * DC);
  float a0 = 0.f, a1 = 0.f, a2 = 0.f, a3 = 0.f;
#pragma unroll 8
  for (int k = 0; k < DC; ++k) {
    float4 xv = *(const float4*)&xs_t[k][0];
    float wv = W[(long)k * DC + d];
    a0 = fmaf(xv.x, wv, a0);
    a1 = fmaf(xv.y, wv, a1);
    a2 = fmaf(xv.z, wv, a2);
    a3 = fmaf(xv.w, wv, a3);
  }
  if (lig) {
    float bv = h ? Bb1[d] : Ab1[d];
    float* Y = h ? UB : UA;
    Y[(long)(r0 + 0) * DC + d] = a0 + bv;
    Y[(long)(r0 + 1) * DC + d] = a1 + bv;
    Y[(long)(r0 + 2) * DC + d] = a2 + bv;
    Y[(long)(r0 + 3) * DC + d] = a3 + bv;
  } else {
    float* V = h ? VBT : VAT;
    int q = bid - 256;
    int b = q >> 6, rin = (q * 4) & 255;
    float* dst = &V[((long)b * DC + d) * N2C + rin];
    dst[0] = a0;
    dst[1] = a1;
    dst[2] = a2;
    dst[3] = a3;
  }
}

// ---------------------------------------------------------------------------
// k_ea2: ea[b,j,k] = e1_j.nt_k + nt_j.e1_k, masked by adjacency at write.
// Register-tiled: 32x64 tile, 256 thr, 2x4 outputs/thread.  Merged
// ligand+target: 64 + 256 = 320 blocks.
// ---------------------------------------------------------------------------
__global__ __launch_bounds__(256) void k_ea2(const float* __restrict__ NTp,
                                             const float* __restrict__ E1p,
                                             const float* __restrict__ ADJL,
                                             const float* __restrict__ ADJT,
                                             float* __restrict__ EAL,
                                             float* __restrict__ EAT) {
  int id = blockIdx.x;
  int N, base, j0, k0, b;
  const float* ADJ;
  float* EA;
  if (id < 64) {
    b = id >> 3;
    int rem = id & 7;
    N = N1C;
    base = b * N1C;
    j0 = (rem >> 1) * 32;
    k0 = (rem & 1) * 64;
    ADJ = ADJL + (long)b * N1C * N1C;
    EA = EAL + (long)b * N1C * N1C;
  } else {
    int q = id - 64;
    b = q >> 5;
    int rem = q & 31;
    N = N2C;
    base = ROWS_L + b * N2C;
    j0 = (rem >> 2) * 32;
    k0 = (rem & 3) * 64;
    ADJ = ADJT + (long)b * N2C * N2C;
    EA = EAT + (long)b * N2C * N2C;
  }
  __shared__ float aj_e1[32][34], aj_nt[32][34];
  __shared__ float bk_e1[32][68], bk_nt[32][68];
  int tid = threadIdx.x, tx = tid & 15, ty = tid >> 4;
  float acc[2][4];
#pragma unroll
  for (int r = 0; r < 2; ++r)
#pragma unroll
    for (int c = 0; c < 4; ++c) acc[r][c] = 0.f;
  for (int kc = 0; kc < DC; kc += 32) {
    __syncthreads();
    for (int t = tid; t < 1024; t += 256) {
      int kk = t & 31, rr = t >> 5;
      aj_e1[kk][rr] = E1p[(long)(base + j0 + rr) * DC + kc + kk];
      aj_nt[kk][rr] = NTp[(long)(base + j0 + rr) * DC + kc + kk];
    }
    for (int t = tid; t < 2048; t += 256) {
      int kk = t & 31, cc = t >> 5;
      bk_e1[kk][cc] = E1p[(long)(base + k0 + cc) * DC + kc + kk];
      bk_nt[kk][cc] = NTp[(long)(base + k0 + cc) * DC + kc + kk];
    }
    __syncthreads();
#pragma unroll
    for (int kk = 0; kk < 32; ++kk) {
      float2 ae = *(const float2*)&aj_e1[kk][ty * 2];
      float2 an = *(const float2*)&aj_nt[kk][ty * 2];
      float4 bn = *(const float4*)&bk_nt[kk][tx * 4];
      float4 be = *(const float4*)&bk_e1[kk][tx * 4];
      acc[0][0] = fmaf(ae.x, bn.x, fmaf(an.x, be.x, acc[0][0]));
      acc[0][1] = fmaf(ae.x, bn.y, fmaf(an.x, be.y, acc[0][1]));
      acc[0][2] = fmaf(ae.x, bn.z, fmaf(an.x, be.z, acc[0][2]));
      acc[0][3] = fmaf(ae.x, bn.w, fmaf(an.x, be.w, acc[0][3]));
      acc[1][0] = fmaf(ae.y, bn.x, fmaf(an.y, be.x, acc[1][0]));
      acc[1][1] = fmaf(ae.y, bn.y, fmaf(an.y, be.y, acc[1][1]));
      acc[1][2] = fmaf(ae.y, bn.z, fmaf(an.y, be.z, acc[1][2]));
      acc[1][3] = fmaf(ae.y, bn.w, fmaf(an.y, be.w, acc[1][3]));
    }
  }
#pragma unroll
  for (int r = 0; r < 2; ++r) {
    long rowi = (long)(j0 + ty * 2 + r) * N + k0 + tx * 4;
    float4 ad = *(const float4*)&ADJ[rowi];
    float4 o;
    o.x = (ad.x > 1e-6f) ? acc[r][0] : -9e15f;
    o.y = (ad.y > 1e-6f) ? acc[r][1] : -9e15f;
    o.z = (ad.z > 1e-6f) ? acc[r][2] : -9e15f;
    o.w = (ad.w > 1e-6f) ? acc[r][3] : -9e15f;
    *(float4*)&EA[rowi] = o;
  }
}

// ---------------------------------------------------------------------------
// k_smagg3: row-softmax + aggregate + gated residual.  16 rows/block,
// 512 threads (16 rowgrp x 32 dgrp x 4 cols).  grid (16, 8, 2).
// ---------------------------------------------------------------------------
__global__ __launch_bounds__(512) void k_smagg3(
    const float* __restrict__ EAL, const float* __restrict__ EAT,
    const float* __restrict__ NTp, const float* __restrict__ Xp,
    const float* __restrict__ GW, const float* __restrict__ GB,
    float* __restrict__ Y) {
  int z = blockIdx.z;
  int N = z ? N2C : N1C;
  if (blockIdx.x * 16 >= N) return;
  int ls = z ? 8 : 7;
  int baseRow = z ? ROWS_L : 0;
  const float* EA = z ? EAT : EAL;
  int b = blockIdx.y, i0 = blockIdx.x * 16;
  __shared__ float ps[16][N2C + 4];
  __shared__ float col[32][DC + 4];
  __shared__ float red[16];
  int tid = threadIdx.x;
  const float* EAb = EA + (long)b * N * N + (long)i0 * N;
  for (int t = tid; t < 16 * N; t += 512)
    ps[t >> ls][t & (N - 1)] = EAb[t];
  __syncthreads();
  int r = tid >> 5, l = tid & 31;  // 16 rows x 32 lanes
  {                                // softmax
    float m = -INFINITY;
    for (int k = l; k < N; k += 32) m = fmaxf(m, ps[r][k]);
#pragma unroll
    for (int o = 16; o > 0; o >>= 1) m = fmaxf(m, __shfl_xor(m, o));
    float s = 0.f;
    for (int k = l; k < N; k += 32) {
      float p = expf(ps[r][k] - m);
      ps[r][k] = p;
      s += p;
    }
#pragma unroll
    for (int o = 16; o > 0; o >>= 1) s += __shfl_xor(s, o);
    float inv = 1.f / s;
    for (int k = l; k < N; k += 32) ps[r][k] *= inv;
  }
  // aggregate: row r, cols d0..d0+3
  int d0 = l * 4;
  float a0 = 0.f, a1 = 0.f, a2 = 0.f, a3 = 0.f;
  const float* NTb = NTp + (long)(baseRow + b * N) * DC;
  for (int k0 = 0; k0 < N; k0 += 32) {
    __syncthreads();
    for (int t = tid; t < 32 * DC; t += 512)
      col[t >> 7][t & 127] = NTb[(long)(k0 + (t >> 7)) * DC + (t & 127)];
    __syncthreads();
#pragma unroll 8
    for (int kk = 0; kk < 32; ++kk) {
      float4 c4 = *(const float4*)&col[kk][d0];
      float p = ps[r][k0 + kk];
      a0 = fmaf(p, c4.x, a0);
      a1 = fmaf(p, c4.y, a1);
      a2 = fmaf(p, c4.z, a2);
      a3 = fmaf(p, c4.w, a3);
    }
  }
  // gate
  float4 gwd = *(const float4*)&GW[d0];
  float4 gwo = *(const float4*)&GW[DC + d0];
  float4 x4 = *(const float4*)&Xp[(long)(baseRow + b * N + i0 + r) * DC + d0];
  float o0 = fmaxf(a0, 0.f), o1 = fmaxf(a1, 0.f);
  float o2 = fmaxf(a2, 0.f), o3 = fmaxf(a3, 0.f);
  float part = x4.x * gwd.x + o0 * gwo.x + x4.y * gwd.y + o1 * gwo.y +
               x4.z * gwd.z + o2 * gwo.z + x4.w * gwd.w + o3 * gwo.w;
#pragma unroll
  for (int o = 16; o > 0; o >>= 1) part += __shfl_xor(part, o);
  if (l == 0) red[r] = part;
  __syncthreads();
  float g = 1.f / (1.f + expf(-(red[r] + GB[0])));
  float4 y;
  y.x = g * x4.x + (1.f - g) * o0;
  y.y = g * x4.y + (1.f - g) * o1;
  y.z = g * x4.z + (1.f - g) * o2;
  y.w = g * x4.w + (1.f - g) * o3;
  *(float4*)&Y[(long)(baseRow + b * N + i0 + r) * DC + d0] = y;
}

// ---------------------------------------------------------------------------
// k_msggru: fused msg + GRU.  8 packed rows per block, 512 threads,
// grid = ROWS_ALL/8 = 384 blocks.
// Phase A: msg = relu(t1 + max_j m2_j*ev_ij) -> xs_t; thread = (32 dgrp x
//          8 rows x 2 j-halves), float4 per thread, j-halves combined via LDS.
// Phase B (tid<384): gi/gh GEMM as TWO sequential 4-row passes (the proven
//          4-accumulator loop; #pragma unroll 1 prevents the 16-acc spill).
// LDS pool union: phase A {m2s, evs, comb} <-> phase B {gis, ghs}.
// ---------------------------------------------------------------------------
__global__ __launch_bounds__(512) void k_msggru(
    const float* __restrict__ T1, const float* __restrict__ M2,
    const float* __restrict__ EV, const float* __restrict__ Hp,
    const float* __restrict__ WihT, const float* __restrict__ WhhT,
    const float* __restrict__ bih, const float* __restrict__ bhh,
    float* __restrict__ Y) {
  int r0 = blockIdx.x * 8;
  __shared__ float pool[6144];  // A: m2s[32][132] (4224) + evs[8][36] (288)
                                //    + comb[256][4] (1024)  = 5536
                                // B: gis[8][384] (3072) + ghs[8][384] (3072)
  __shared__ float xs_t[DC][8], hs_t[DC][8];
  float* m2s = pool;            // [32][132]
  float* evs = pool + 4224;     // [8][36]
  float* comb = pool + 4512;    // [256][4]
  float* gis = pool;            // [8][384]
  float* ghs = pool + 3072;
  int tid = threadIdx.x;
  int m2base, b, i0in, ntile;
  long ev_is, ev_js;
  if (r0 < ROWS_L) {  // ligand update: msg over target atoms
    b = r0 >> 7;
    i0in = r0 & 127;
    ntile = N2C / 32;
    m2base = ROWS_L + b * N2C;
    ev_is = N2C;
    ev_js = 1;
  } else {  // target update: msg over ligand atoms (transposed EV)
    int q = r0 - ROWS_L;
    b = q >> 8;
    i0in = q & 255;
    ntile = N1C / 32;
    m2base = b * N1C;
    ev_is = 1;
    ev_js = N2C;
  }
  const float* EVb = EV + (long)b * (N1C * N2C);
  // Phase A mapping: dgrp (4 cols), row, j-half
  int dgrp = tid & 31, row = (tid >> 5) & 7, jh = tid >> 8;
  int d0 = dgrp * 4;
  float4 acc;
  acc.x = -INFINITY; acc.y = -INFINITY; acc.z = -INFINITY; acc.w = -INFINITY;
  for (int jt = 0; jt < ntile; ++jt) {
    int j0 = jt * 32;
    __syncthreads();
    for (int t = tid; t < 32 * DC; t += 512)
      m2s[(t >> 7) * 132 + (t & 127)] =
          M2[(long)(m2base + j0 + (t >> 7)) * DC + (t & 127)];
    if (tid < 256)
      evs[(tid >> 5) * 36 + (tid & 31)] =
          EVb[(long)(i0in + (tid >> 5)) * ev_is +
              (long)(j0 + (tid & 31)) * ev_js];
    __syncthreads();
    int jb = jh * 16;
#pragma unroll 8
    for (int jj = 0; jj < 16; ++jj) {
      float4 m4 = *(const float4*)&m2s[(jb + jj) * 132 + d0];
      float e = evs[row * 36 + jb + jj];
      acc.x = fmaxf(acc.x, m4.x * e);
      acc.y = fmaxf(acc.y, m4.y * e);
      acc.z = fmaxf(acc.z, m4.z * e);
      acc.w = fmaxf(acc.w, m4.w * e);
    }
  }
  __syncthreads();
  if (jh == 1) {
    float* dst = &comb[(tid - 256) * 4];
    dst[0] = acc.x; dst[1] = acc.y; dst[2] = acc.z; dst[3] = acc.w;
  }
  __syncthreads();
  if (jh == 0) {
    const float* src = &comb[tid * 4];
    acc.x = fmaxf(acc.x, src[0]);
    acc.y = fmaxf(acc.y, src[1]);
    acc.z = fmaxf(acc.z, src[2]);
    acc.w = fmaxf(acc.w, src[3]);
    float4 t4 = *(const float4*)&T1[(long)(r0 + row) * DC + d0];
    xs_t[d0 + 0][row] = fmaxf(t4.x + acc.x, 0.f);
    xs_t[d0 + 1][row] = fmaxf(t4.y + acc.y, 0.f);
    xs_t[d0 + 2][row] = fmaxf(t4.z + acc.z, 0.f);
    xs_t[d0 + 3][row] = fmaxf(t4.w + acc.w, 0.f);
  }
  for (int t = tid; t < 8 * DC; t += 512)
    hs_t[t & 127][t >> 7] = Hp[(long)(r0 + (t >> 7)) * DC + (t & 127)];
  __syncthreads();
  // Phase B: two 4-row GEMM passes (proven inner loop)
  if (tid < 384) {
    int dd = tid;
    float bi = bih[dd], bh = bhh[dd];
#pragma unroll 1
    for (int pass = 0; pass < 2; ++pass) {
      int rb = pass * 4;
      float ai[4] = {0.f, 0.f, 0.f, 0.f}, ah[4] = {0.f, 0.f, 0.f, 0.f};
#pragma unroll 8
      for (int k = 0; k < DC; ++k) {
        float4 xv = *(const float4*)&xs_t[k][rb];
        float4 hv = *(const float4*)&hs_t[k][rb];
        float wi = WihT[(long)k * 384 + dd];
        float wh = WhhT[(long)k * 384 + dd];
        ai[0] = fmaf(xv.x, wi, ai[0]);
        ai[1] = fmaf(xv.y, wi, ai[1]);
        ai[2] = fmaf(xv.z, wi, ai[2]);
        ai[3] = fmaf(xv.w, wi, ai[3]);
        ah[0] = fmaf(hv.x, wh, ah[0]);
        ah[1] = fmaf(hv.y, wh, ah[1]);
        ah[2] = fmaf(hv.z, wh, ah[2]);
        ah[3] = fmaf(hv.w, wh, ah[3]);
      }
#pragma unroll
      for (int rr = 0; rr < 4; ++rr) {
        gis[(rb + rr) * 384 + dd] = ai[rr] + bi;
        ghs[(rb + rr) * 384 + dd] = ah[rr] + bh;
      }
    }
  }
  __syncthreads();
  for (int t = tid; t < 8 * DC; t += 512) {
    int rr = t >> 7, dq = t & 127;
    float ir = gis[rr * 384 + dq], iz = gis[rr * 384 + dq + 128],
          inn = gis[rr * 384 + dq + 256];
    float hr = ghs[rr * 384 + dq], hz = ghs[rr * 384 + dq + 128],
          hn = ghs[rr * 384 + dq + 256];
    float rg = 1.f / (1.f + expf(-(ir + hr)));
    float zg = 1.f / (1.f + expf(-(iz + hz)));
    float ng = tanhf(inn + rg * hn);
    Y[(long)(r0 + rr) * DC + dq] = (1.f - zg) * ng + zg * hs_t[dq][rr];
  }
}

// ---------------------------------------------------------------------------
// Pairwise physics + analytic grad/Hessian partials.  2 ligand atoms per
// block.  grid (64, 8), 256 threads (j).
// ---------------------------------------------------------------------------
__global__ __launch_bounds__(256) void k_pair(
    const float* __restrict__ UA, const float* __restrict__ VAT,
    const float* __restrict__ UB, const float* __restrict__ VBT,
    const float* __restrict__ AW2, const float* __restrict__ AB2,
    const float* __restrict__ BW2, const float* __restrict__ BB2,
    const float* __restrict__ LP, const float* __restrict__ TP,
    const float* __restrict__ LVDW, const float* __restrict__ TVDW,
    const float* __restrict__ LNM, const float* __restrict__ TNM,
    const float* __restrict__ II, const float* __restrict__ HBC,
    const float* __restrict__ HPC, float* __restrict__ PART) {
  const int D = DC, N1 = N1C, N2 = N2C;
  int i0 = blockIdx.x * 2, b = blockIdx.y, j = threadIdx.x;
  __shared__ float ua[2][128], ub[2][128], wa2[128], wb2[128];
  if (j < 128) {
    long rb = ((long)b * N1 + i0) * D + j;
    ua[0][j] = UA[rb];
    ub[0][j] = UB[rb];
    wa2[j] = AW2[j];
    wb2[j] = BW2[j];
  } else {
    int jj = j - 128;
    long rb = ((long)b * N1 + i0 + 1) * D + jj;
    ua[1][jj] = UA[rb];
    ub[1][jj] = UB[rb];
  }
  __syncthreads();
  const float* vat = VAT + (long)b * D * N2;
  const float* vbt = VBT + (long)b * D * N2;
  float dotA[2] = {0.f, 0.f}, dotB[2] = {0.f, 0.f};
#pragma unroll 4
  for (int d = 0; d < D; ++d) {
    float va = vat[(long)d * N2 + j];
    float vb = vbt[(long)d * N2 + j];
    dotA[0] += fmaxf(ua[0][d] + va, 0.f) * wa2[d];
    dotA[1] += fmaxf(ua[1][d] + va, 0.f) * wa2[d];
    dotB[0] += fmaxf(ub[0][d] + vb, 0.f) * wb2[d];
    dotB[1] += fmaxf(ub[1][d] + vb, 0.f) * wb2[d];
  }
  float hb2 = HBC[0] * HBC[0], hp2 = HPC[0] * HPC[0];
  float tx = TP[((long)b * N2 + j) * 3 + 0];
  float ty = TP[((long)b * N2 + j) * 3 + 1];
  float tz = TP[((long)b * N2 + j) * 3 + 2];
  float tvd = TVDW[b * N2 + j];
  float tnm = TNM[b * N2 + j];
  float res[2][8];
#pragma unroll
  for (int ii = 0; ii < 2; ++ii) {
    int i = i0 + ii;
    float A_raw = 1.f / (1.f + expf(-(dotA[ii] + AB2[0])));
    float A_vdw = A_raw * (0.0356f - 0.0178f) + 0.0178f;
    float B_raw = tanhf(dotB[ii] + BB2[0]) * 0.2f;

    float lx = LP[((long)b * N1 + i) * 3 + 0];
    float ly = LP[((long)b * N1 + i) * 3 + 1];
    float lz = LP[((long)b * N1 + i) * 3 + 2];
    float dx = lx - tx, dy = ly - ty, dz = lz - tz;
    float s2 = dx * dx + dy * dy + dz * dz + 1e-10f;
    float draw = sqrtf(s2);
    bool clamped = draw < 0.5f;
    float dmv = clamped ? 1e10f : draw;

    float dm0 = LVDW[b * N1 + i] + tvd + B_raw;
    float dm0c = (dm0 < 1e-4f) ? 1.f : dm0;
    float valid = LNM[b * N1 + i] * tnm;

    float rr = dm0c / dmv;
    float r2 = rr * rr, r6 = r2 * r2 * r2;
    float fv = r6 * r6 - 2.f * r6;
    float evdw = A_vdw * (fminf(fv, 100.f) * valid);

    float dmd = dmv - dm0;
    long ii0x = ((long)b * 3) * N1 * N2 + (long)i * N2 + j;
    float I0 = II[ii0x];
    float I1 = II[ii0x + (long)N1 * N2];
    float I2 = II[ii0x + 2L * N1 * N2];
    float u0 = dmd * I0 / (-0.7f);
    float u1 = dmd * I1 / (-0.7f);
    float vv = (1.5f - dmd) * I2;
    float ehb = fminf(fmaxf(u0, 0.f), 1.f) * (-hb2);
    float emt = fminf(fmaxf(u1, 0.f), 1.f) * (-hb2);
    float ehp = fminf(fmaxf(vv, 0.f), 1.f) * (-hp2);

    float gx = 0.f, gy = 0.f, gz = 0.f, d2t = 0.f;
    if (!clamped) {
      float Ep = 0.f, Epp = 0.f;
      if (fv < 100.f) {
        float c = A_vdw * valid;
        Ep += c * (-12.f) * r6 * (r6 - 1.f) / draw;
        Epp += c * r6 * (156.f * r6 - 84.f) / s2;
      }
      if (u0 > 0.f && u0 < 1.f) Ep += hb2 * I0 * (1.f / 0.7f);
      if (u1 > 0.f && u1 < 1.f) Ep += hb2 * I1 * (1.f / 0.7f);
      if (vv > 0.f && vv < 1.f) Ep += hp2 * I2;
      float invd = 1.f / draw;
      gx = Ep * dx * invd;
      gy = Ep * dy * invd;
      gz = Ep * dz * invd;
      float T = dx + dy + dz;
      float tt = T * T / s2;
      d2t = Epp * tt + Ep * (3.f - tt) * invd;
    }
    res[ii][0] = evdw;
    res[ii][1] = ehb;
    res[ii][2] = emt;
    res[ii][3] = ehp;
    res[ii][4] = gx;
    res[ii][5] = gy;
    res[ii][6] = gz;
    res[ii][7] = d2t;
  }
#pragma unroll
  for (int ii = 0; ii < 2; ++ii) {
    float o[8];
#pragma unroll
    for (int q = 0; q < 8; ++q) o[q] = blockSum(res[ii][q]);
    if (j == 0) {
      float* p = PART + ((long)b * N1 + i0 + ii) * 8;
#pragma unroll
      for (int q = 0; q < 8; ++q) p[q] = o[q];
    }
  }
}

// final deterministic reduction + output assembly (34 floats)
__global__ void k_final(const float* __restrict__ PART, const float* __restrict__ ROT,
                        const float* __restrict__ RC, float* __restrict__ OUT) {
  const int N1 = N1C;
  __shared__ float s[8][8];
  int t = threadIdx.x;
  if (t < 64) {
    int b = t >> 3, k1 = t & 7;
    float acc = 0.f;
    for (int i = 0; i < N1; ++i) acc += PART[((long)b * N1 + i) * 8 + k1];
    s[b][k1] = acc;
  }
  __syncthreads();
  if (t == 0) {
    float rcc = RC[0] * RC[0];
    float der1 = 0.f, der2 = 0.f;
    for (int b = 0; b < 8; ++b) {
      float w = 1.f / (1.f + rcc * ROT[b]);
      OUT[b * 4 + 0] = s[b][0] * w;
      OUT[b * 4 + 1] = s[b][1] * w;
      OUT[b * 4 + 2] = s[b][2] * w;
      OUT[b * 4 + 3] = s[b][3] * w;
      for (int c = 0; c < 3; ++c) {
        float S = s[b][4 + c] * w;
        der1 += S * S;
      }
      der2 += s[b][7] * w;
    }
    OUT[32] = der1 / 24.f;
    OUT[33] = -der2 / 8.f;
  }
}

// ---------------------------------------------------------------------------
// Host-side orchestration
// ---------------------------------------------------------------------------
extern "C" void kernel_launch(void* const* d_in, const int* in_sizes, int n_in,
                              void* d_out, int out_size, void* d_ws, size_t ws_size,
                              hipStream_t stream) {
  (void)in_sizes; (void)n_in; (void)out_size; (void)ws_size;
  const int D = DC;

  const float* ligand_h   = (const float*)d_in[0];
  const float* ligand_adj = (const float*)d_in[1];
  const float* target_h   = (const float*)d_in[2];
  const float* target_adj = (const float*)d_in[3];
  const float* inter_ind  = (const float*)d_in[4];
  const float* ligand_pos = (const float*)d_in[5];
  const float* target_pos = (const float*)d_in[6];
  const float* rotor      = (const float*)d_in[7];
  const float* lvdw       = (const float*)d_in[8];
  const float* tvdw       = (const float*)d_in[9];
  const float* lnm        = (const float*)d_in[12];
  const float* tnm        = (const float*)d_in[13];
  const float* emb_w      = (const float*)d_in[14];
  const float* gat_w      = (const float*)d_in[15];
  const float* gat_b      = (const float*)d_in[16];
  const float* gat_att    = (const float*)d_in[17];
  const float* gat_gate_w = (const float*)d_in[18];
  const float* gat_gate_b = (const float*)d_in[19];
  const float* int_wt_w   = (const float*)d_in[20];
  const float* int_wt_b   = (const float*)d_in[21];
  const float* int_mt_w   = (const float*)d_in[22];
  const float* int_mt_b   = (const float*)d_in[23];
  const float* gru_w_ih   = (const float*)d_in[24];
  const float* gru_w_hh   = (const float*)d_in[25];
  const float* gru_b_ih   = (const float*)d_in[26];
  const float* gru_b_hh   = (const float*)d_in[27];
  const float* A_w1       = (const float*)d_in[28];
  const float* A_b1       = (const float*)d_in[29];
  const float* A_w2       = (const float*)d_in[30];
  const float* A_b2       = (const float*)d_in[31];
  const float* B_w1       = (const float*)d_in[32];
  const float* B_b1       = (const float*)d_in[33];
  const float* B_w2       = (const float*)d_in[34];
  const float* B_b2       = (const float*)d_in[35];
  const float* hb_c       = (const float*)d_in[36];
  const float* hp_c       = (const float*)d_in[37];
  const float* rc_c       = (const float*)d_in[38];

  // workspace carve (floats)
  float* w = (float*)d_ws;
  auto take = [&](size_t n) { float* p = w; w += n; return p; };
  float* H0    = take((size_t)ROWS_ALL * DC);   // 393216
  float* H1    = take((size_t)ROWS_ALL * DC);
  float* NT    = take((size_t)ROWS_ALL * DC);
  float* E1    = take((size_t)ROWS_ALL * DC);
  float* EAL   = take((size_t)BB * N1C * N1C);  // 131072
  float* EAT   = take((size_t)BB * N2C * N2C);  // 524288
  float* ADJ12 = take((size_t)BB * N1C * N2C);  // 262144
  float* WA    = take((size_t)3 * DC * DC);     // 49152
  float* bA    = take((size_t)3 * DC);
  float* GIHT  = take((size_t)3 * DC * 384);    // 147456
  float* GHHT  = take((size_t)3 * DC * 384);
  float* PART  = take((size_t)BB * N1C * 8);
  // phase-disjoint aliases
  float* T1  = NT;
  float* M2  = E1;
  float* UA  = EAL;           // 131072
  float* UB  = EAT;           // 131072 (front of EAT)
  float* VAT = NT;            // 262144 <= 393216
  float* VBT = E1;            // 262144

  // merged prep: adj12 + embedding + WA fuse + GRU weight transposes
  k_prep<<<2659, 256, 0, stream>>>(ligand_pos, target_pos, ADJ12, ligand_h,
                                   target_h, emb_w, H0, gat_w, gat_b, gat_att,
                                   WA, bA, gru_w_ih, gru_w_hh, GIHT, GHHT);

  float *cur = H0, *alt = H1;

  // GAT stack (3 layers)
  for (int l = 0; l < 3; ++l) {
    k_lin2h<<<ROWS_ALL / 4, 256, 0, stream>>>(
        cur, gat_w + (size_t)l * D * D, gat_b + l * D, WA + (size_t)l * D * D,
        bA + l * D, NT, E1);
    k_ea2<<<320, 256, 0, stream>>>(NT, E1, ligand_adj, target_adj, EAL, EAT);
    k_smagg3<<<dim3(N2C / 16, BB, 2), 512, 0, stream>>>(
        EAL, EAT, NT, cur, gat_gate_w + l * 2 * D, gat_gate_b + l, alt);
    float* t = cur; cur = alt; alt = t;
  }

  // interaction layers (both directions use OLD h; msg+gru fused, 8 rows)
  for (int l = 0; l < 3; ++l) {
    k_lin2h<<<ROWS_ALL / 4, 256, 0, stream>>>(
        cur, int_wt_w + (size_t)l * D * D, int_wt_b + l * D,
        int_mt_w + (size_t)l * D * D, int_mt_b + l * D, T1, M2);
    k_msggru<<<ROWS_ALL / 8, 512, 0, stream>>>(
        T1, M2, ADJ12, cur, GIHT + (size_t)l * D * 384,
        GHHT + (size_t)l * D * 384, gru_b_ih + l * 384, gru_b_hh + l * 384,
        alt);
    float* t = cur; cur = alt; alt = t;
  }

  // pairwise feature heads, single dispatch (U normal, V transposed [b][d][j])
  k_featall<<<768, 256, 0, stream>>>(cur, A_w1, A_b1, B_w1, B_b1, UA, UB, VAT,
                                     VBT);

  // pairwise physics + analytic derivatives (2 atoms/block)
  k_pair<<<dim3(N1C / 2, BB), 256, 0, stream>>>(UA, VAT, UB, VBT, A_w2, A_b2,
                                                B_w2, B_b2, ligand_pos,
                                                target_pos, lvdw, tvdw, lnm,
                                                tnm, inter_ind, hb_c, hp_c,
                                                PART);

  // final reduction -> 34 outputs
  k_final<<<1, 256, 0, stream>>>(PART, rotor, rc_c, (float*)d_out);
}